// Round 3
// baseline (387.191 us; speedup 1.0000x reference)
//
#include <hip/hip_runtime.h>
#include <hip/hip_bf16.h>
#include <stdint.h>

typedef float f32x4 __attribute__((ext_vector_type(4)));
typedef __bf16 bf16x8 __attribute__((ext_vector_type(8)));
typedef __bf16 bf16x2 __attribute__((ext_vector_type(2)));

#define NB 8
#define NC 192
#define NO 576
#define NH 128
#define NWID 128
#define NSP 16384
#define NHEADS 4
#define NCH 48

// workspace layout (bytes)
#define OFF_KV    0u
#define OFF_SSQ   12288u
#define OFF_S     24576u        // 294912 B
#define OFF_WB    319488u       // 221184 B
#define OFF_M     540672u       // 589824 B
#define OFF_XT    1130496u      // xt: 50331648 B; qkv2 aliases (xt dead by then): 150994944 B
#define OFF_QKV1  152125440u    // qkv1: 150994944 B; vT aliases (qkv1 dead after k_dw): 50331648 B

// ---------------- kernel 1: kv = prior @ w_kernel^T  (8 x 384) ----------------
__global__ void k_kv(const float* __restrict__ prior, const float* __restrict__ w_kernel,
                     float* __restrict__ kv) {
    int t = blockIdx.x * 256 + threadIdx.x;
    if (t >= NB * 384) return;
    int b = t / 384, j = t % 384;
    const float* p = prior + b * NC;
    const float* wk = w_kernel + j * NC;
    float s = 0.f;
    for (int f = 0; f < NC; ++f) s += p[f] * wk[f];
    kv[t] = s;
}

// ---------------- kernel 2: cast w_qkv -> bf16 ----------------
__global__ void k_wcast(const float* __restrict__ w_qkv, __bf16* __restrict__ Wb) {
    int t = blockIdx.x * 256 + threadIdx.x;
    if (t < NO * NC) Wb[t] = (__bf16)w_qkv[t];
}

// ---------------- kernel 3: x~ = x*kv1 + kv2, transposed to [b][n][c] bf16 ----------------
// LDS XOR-swizzle: element (n,c) stored at byte n*384 + (((c>>3) ^ ((n>>2)&7))<<4) + ((c&7)<<1)
__global__ __launch_bounds__(256) void k_xt(const float* __restrict__ x, const float* __restrict__ kv,
                                            __bf16* __restrict__ xt) {
    int b = blockIdx.y;
    int n0 = blockIdx.x * 128;
    __shared__ __align__(16) __bf16 lds[128 * 192];
    int t = threadIdx.x;
    for (int p = 0; p < 24; ++p) {
        int id = p * 256 + t;
        int c = id >> 5, n4 = (id & 31) << 2;
        f32x4 v = *reinterpret_cast<const f32x4*>(x + (size_t)(b * NC + c) * NSP + n0 + n4);
        float k1 = kv[b * 384 + c], k2 = kv[b * 384 + 192 + c];
        int chi = (c >> 3) ^ ((n4 >> 2) & 7);   // swizzled 16B-chunk index (n>>2 const for j<4)
        int base = chi * 16 + (c & 7) * 2;
#pragma unroll
        for (int j = 0; j < 4; ++j)
            *reinterpret_cast<__bf16*>((char*)lds + (n4 + j) * 384 + base) = (__bf16)(v[j] * k1 + k2);
    }
    __syncthreads();
    for (int p = 0; p < 12; ++p) {
        int id = p * 256 + t;
        int n = id / 24, k = id % 24;
        bf16x8 r = *reinterpret_cast<const bf16x8*>((char*)lds + n * 384 + ((k ^ ((n >> 2) & 7)) << 4));
        *reinterpret_cast<bf16x8*>(xt + (size_t)(b * NSP + n0 + n) * NC + k * 8) = r;
    }
}

// ---------------- kernel 4: qkv GEMM, full register preload ----------------
__global__ __launch_bounds__(256, 2) void k_qkv(const __bf16* __restrict__ xt, const __bf16* __restrict__ Wb,
                                                __bf16* __restrict__ qkv1) {
    int b = blockIdx.z;
    int o0 = blockIdx.x * 64;
    int tid = threadIdx.x, w = tid >> 6, l = tid & 63, lr = l & 15, lg = l >> 4;
    int n0 = blockIdx.y * 128 + w * 32;
    const __bf16* abase = Wb + (size_t)(o0 + lr) * NC + lg * 8;
    const __bf16* bbase = xt + (size_t)(b * NSP + n0 + lr) * NC + lg * 8;
    bf16x8 ag[6][4], bg[6][2];
#pragma unroll
    for (int ks = 0; ks < 6; ++ks) {
#pragma unroll
        for (int mf = 0; mf < 4; ++mf)
            ag[ks][mf] = *reinterpret_cast<const bf16x8*>(abase + (size_t)mf * 16 * NC + ks * 32);
#pragma unroll
        for (int nf = 0; nf < 2; ++nf)
            bg[ks][nf] = *reinterpret_cast<const bf16x8*>(bbase + (size_t)nf * 16 * NC + ks * 32);
    }
    f32x4 acc[4][2] = {};
#pragma unroll
    for (int ks = 0; ks < 6; ++ks)
#pragma unroll
        for (int mf = 0; mf < 4; ++mf)
#pragma unroll
            for (int nf = 0; nf < 2; ++nf)
                acc[mf][nf] = __builtin_amdgcn_mfma_f32_16x16x32_bf16(ag[ks][mf], bg[ks][nf], acc[mf][nf], 0, 0, 0);
#pragma unroll
    for (int mf = 0; mf < 4; ++mf)
#pragma unroll
        for (int r = 0; r < 4; ++r) {
            int orow = o0 + mf * 16 + lg * 4 + r;
#pragma unroll
            for (int nf = 0; nf < 2; ++nf)
                qkv1[(size_t)(b * NO + orow) * NSP + n0 + nf * 16 + lr] = (__bf16)acc[mf][nf][r];
        }
}

// ---------------- kernel 5: depthwise 3x3 conv + sumsq(q,k), register-rolling ----------------
__global__ __launch_bounds__(256) void k_dw(const __bf16* __restrict__ qkv1, const float* __restrict__ w_dw,
                                            __bf16* __restrict__ qkv2, float* __restrict__ ssq) {
    int task = blockIdx.x * 4 + (threadIdx.x >> 6);
    int l = threadIdx.x & 63;
    int strip = task & 7;
    int bo = task >> 3;
    int o = bo % NO, b = bo / NO;
    const __bf16* src = qkv1 + (size_t)bo * NSP;
    __bf16* dst = qkv2 + (size_t)bo * NSP;
    float wd[9];
#pragma unroll
    for (int i = 0; i < 9; ++i) wd[i] = w_dw[o * 9 + i];
    int ys = strip * 16;
    float a0, b0, L0, R0, a1, b1, L1, R1, a2, b2, L2, R2;

#define LOADROW(Y, A, B, L_, R_) {                                            \
        bf16x2 p = {};                                                        \
        int y_ = (Y);                                                         \
        if (y_ >= 0 && y_ < NH) p = *reinterpret_cast<const bf16x2*>(src + y_ * NWID + 2 * l); \
        A = (float)p[0]; B = (float)p[1];                                     \
        L_ = __shfl(B, l - 1); R_ = __shfl(A, l + 1);                         \
        if (l == 0) L_ = 0.f;                                                 \
        if (l == 63) R_ = 0.f; }

    LOADROW(ys - 1, a0, b0, L0, R0)
    LOADROW(ys,     a1, b1, L1, R1)
    float ss = 0.f;
    bool qk = (o < 384);
#pragma unroll 4
    for (int i = 0; i < 16; ++i) {
        LOADROW(ys + i + 1, a2, b2, L2, R2)
        float oa = L0 * wd[0] + a0 * wd[1] + b0 * wd[2]
                 + L1 * wd[3] + a1 * wd[4] + b1 * wd[5]
                 + L2 * wd[6] + a2 * wd[7] + b2 * wd[8];
        float ob = a0 * wd[0] + b0 * wd[1] + R0 * wd[2]
                 + a1 * wd[3] + b1 * wd[4] + R1 * wd[5]
                 + a2 * wd[6] + b2 * wd[7] + R2 * wd[8];
        bf16x2 ov; ov[0] = (__bf16)oa; ov[1] = (__bf16)ob;
        *reinterpret_cast<bf16x2*>(dst + (ys + i) * NWID + 2 * l) = ov;
        if (qk) { float fa = (float)ov[0], fb = (float)ov[1]; ss += fa * fa + fb * fb; }
        a0 = a1; b0 = b1; L0 = L1; R0 = R1;
        a1 = a2; b1 = b2; L1 = L2; R1 = R2;
    }
#undef LOADROW
    if (qk) {
        for (int off = 32; off > 0; off >>= 1) ss += __shfl_down(ss, off);
        if (l == 0) atomicAdd(&ssq[b * 384 + o], ss);
    }
}

// ---------------- kernel 6: transpose v -> vT [b][n][c] (aliases dead qkv1) ----------------
__global__ __launch_bounds__(256) void k_vt(const __bf16* __restrict__ qkv2, __bf16* __restrict__ vt) {
    int b = blockIdx.y;
    int n0 = blockIdx.x * 128;
    __shared__ __align__(16) __bf16 lds[128 * 192];
    int t = threadIdx.x;
    for (int p = 0; p < 12; ++p) {
        int id = p * 256 + t;
        int c = id >> 4, n8 = (id & 15) << 3;
        bf16x8 v = *reinterpret_cast<const bf16x8*>(qkv2 + (size_t)(b * NO + 384 + c) * NSP + n0 + n8);
        int chi = (c >> 3) ^ ((n8 >> 3) & 7);   // n>>3 const for j<8
        int base = chi * 16 + (c & 7) * 2;
#pragma unroll
        for (int j = 0; j < 8; ++j)
            *reinterpret_cast<__bf16*>((char*)lds + (n8 + j) * 384 + base) = v[j];
    }
    __syncthreads();
    for (int p = 0; p < 12; ++p) {
        int id = p * 256 + t;
        int n = id / 24, k = id % 24;
        bf16x8 r = *reinterpret_cast<const bf16x8*>((char*)lds + n * 384 + ((k ^ ((n >> 3) & 7)) << 4));
        *reinterpret_cast<bf16x8*>(vt + (size_t)(b * NSP + n0 + n) * NC + k * 8) = r;
    }
}

// ---------------- kernel 7: raw Gram dots S[b,h,c,d], register preload ----------------
__global__ __launch_bounds__(256, 3) void k_sdot(const __bf16* __restrict__ qkv2, float* __restrict__ S) {
    int b = blockIdx.z, h = blockIdx.y;
    int tid = threadIdx.x, w = tid >> 6, l = tid & 63, lr = l & 15, lg = l >> 4;
    const __bf16* qbase = qkv2 + (size_t)(b * NO + h * NCH) * NSP;
    const __bf16* kbase = qkv2 + (size_t)(b * NO + 192 + h * NCH) * NSP;
    int nb0 = blockIdx.x * 512 + w * 128 + lg * 8;
    bf16x8 ag[4][3], bg[4][3];
#pragma unroll
    for (int ks = 0; ks < 4; ++ks) {
        int nb = nb0 + ks * 32;
#pragma unroll
        for (int mf = 0; mf < 3; ++mf)
            ag[ks][mf] = *reinterpret_cast<const bf16x8*>(qbase + (size_t)(mf * 16 + lr) * NSP + nb);
#pragma unroll
        for (int nf = 0; nf < 3; ++nf)
            bg[ks][nf] = *reinterpret_cast<const bf16x8*>(kbase + (size_t)(nf * 16 + lr) * NSP + nb);
    }
    f32x4 acc[3][3] = {};
#pragma unroll
    for (int ks = 0; ks < 4; ++ks)
#pragma unroll
        for (int mf = 0; mf < 3; ++mf)
#pragma unroll
            for (int nf = 0; nf < 3; ++nf)
                acc[mf][nf] = __builtin_amdgcn_mfma_f32_16x16x32_bf16(ag[ks][mf], bg[ks][nf], acc[mf][nf], 0, 0, 0);
    __shared__ float red[4][48][49];
#pragma unroll
    for (int mf = 0; mf < 3; ++mf)
#pragma unroll
        for (int nf = 0; nf < 3; ++nf)
#pragma unroll
            for (int r = 0; r < 4; ++r) {
                int c = mf * 16 + lg * 4 + r, d = nf * 16 + lr;
                red[w][c][d] = acc[mf][nf][r];
            }
    __syncthreads();
    float* Sb = S + (size_t)(b * NHEADS + h) * NCH * NCH;
    for (int i = 0; i < 9; ++i) {
        int idx = tid + i * 256;
        int c = idx / 48, d = idx % 48;
        float s = red[0][c][d] + red[1][c][d] + red[2][c][d] + red[3][c][d];
        atomicAdd(&Sb[c * 48 + d], s);
    }
}

// ---------------- kernel 8: normalize + softmax + fold proj ----------------
__global__ __launch_bounds__(256) void k_soft(const float* __restrict__ S, const float* __restrict__ ssq,
                                              const float* __restrict__ temp, const float* __restrict__ w_proj,
                                              __bf16* __restrict__ M) {
    int b = blockIdx.x / NHEADS, h = blockIdx.x % NHEADS;
    int tid = threadIdx.x;
    __shared__ float attn[48][48];
    __shared__ float inv[96];
    if (tid < 96) {
        int c = tid % 48;
        int isK = tid / 48;
        float v = ssq[b * 384 + isK * 192 + h * NCH + c];
        float nrm = fmaxf(sqrtf(v), 1e-12f);
        inv[tid] = 1.f / nrm;
    }
    __syncthreads();
    float tp = temp[h];
    const float* Sb = S + (size_t)(b * NHEADS + h) * NCH * NCH;
    for (int i = 0; i < 9; ++i) {
        int idx = tid + i * 256;
        int c = idx / 48, d = idx % 48;
        attn[c][d] = Sb[c * 48 + d] * inv[c] * inv[48 + d] * tp;
    }
    __syncthreads();
    if (tid < 48) {
        float m = -1e30f;
        for (int d = 0; d < 48; ++d) m = fmaxf(m, attn[tid][d]);
        float sum = 0.f;
        for (int d = 0; d < 48; ++d) { float e = __expf(attn[tid][d] - m); attn[tid][d] = e; sum += e; }
        float r = 1.f / sum;
        for (int d = 0; d < 48; ++d) attn[tid][d] *= r;
    }
    __syncthreads();
    for (int i = 0; i < 36; ++i) {
        int idx = tid + i * 256;
        int oo = idx / 48, d = idx % 48;
        const float* wp = w_proj + oo * NC + h * NCH;
        float s = 0.f;
        for (int c = 0; c < 48; ++c) s += wp[c] * attn[c][d];
        M[(size_t)(b * NC + oo) * NC + h * NCH + d] = (__bf16)s;
    }
}

// ---------------- kernel 9: final GEMM, full register preload ----------------
__global__ __launch_bounds__(256, 2) void k_out(const __bf16* __restrict__ Mw, const __bf16* __restrict__ vt,
                                                float* __restrict__ outp) {
    int b = blockIdx.z;
    int o0 = blockIdx.x * 64;
    int tid = threadIdx.x, w = tid >> 6, l = tid & 63, lr = l & 15, lg = l >> 4;
    int n0 = blockIdx.y * 128 + w * 32;
    const __bf16* abase = Mw + (size_t)(b * NC + o0 + lr) * NC + lg * 8;
    const __bf16* bbase = vt + (size_t)(b * NSP + n0 + lr) * NC + lg * 8;
    bf16x8 ag[6][4], bg[6][2];
#pragma unroll
    for (int ks = 0; ks < 6; ++ks) {
#pragma unroll
        for (int mf = 0; mf < 4; ++mf)
            ag[ks][mf] = *reinterpret_cast<const bf16x8*>(abase + (size_t)mf * 16 * NC + ks * 32);
#pragma unroll
        for (int nf = 0; nf < 2; ++nf)
            bg[ks][nf] = *reinterpret_cast<const bf16x8*>(bbase + (size_t)nf * 16 * NC + ks * 32);
    }
    f32x4 acc[4][2] = {};
#pragma unroll
    for (int ks = 0; ks < 6; ++ks)
#pragma unroll
        for (int mf = 0; mf < 4; ++mf)
#pragma unroll
            for (int nf = 0; nf < 2; ++nf)
                acc[mf][nf] = __builtin_amdgcn_mfma_f32_16x16x32_bf16(ag[ks][mf], bg[ks][nf], acc[mf][nf], 0, 0, 0);
#pragma unroll
    for (int mf = 0; mf < 4; ++mf)
#pragma unroll
        for (int r = 0; r < 4; ++r) {
            int orow = o0 + mf * 16 + lg * 4 + r;
#pragma unroll
            for (int nf = 0; nf < 2; ++nf)
                outp[(size_t)(b * NC + orow) * NSP + n0 + nf * 16 + lr] = acc[mf][nf][r];
        }
}

extern "C" void kernel_launch(void* const* d_in, const int* in_sizes, int n_in,
                              void* d_out, int out_size, void* d_ws, size_t ws_size,
                              hipStream_t stream) {
    const float* x        = (const float*)d_in[0];
    const float* prior    = (const float*)d_in[1];
    const float* w_qkv    = (const float*)d_in[2];
    const float* w_dw     = (const float*)d_in[3];
    const float* w_proj   = (const float*)d_in[4];
    const float* w_kernel = (const float*)d_in[5];
    const float* temp     = (const float*)d_in[6];
    char* ws = (char*)d_ws;
    float*  kv    = (float*)(ws + OFF_KV);
    float*  ssq   = (float*)(ws + OFF_SSQ);
    float*  S     = (float*)(ws + OFF_S);
    __bf16* Wb    = (__bf16*)(ws + OFF_WB);
    __bf16* M     = (__bf16*)(ws + OFF_M);
    __bf16* xt    = (__bf16*)(ws + OFF_XT);
    __bf16* qkv2  = (__bf16*)(ws + OFF_XT);    // aliases xt (xt dead after k_qkv)
    __bf16* qkv1  = (__bf16*)(ws + OFF_QKV1);
    __bf16* vt    = (__bf16*)(ws + OFF_QKV1);  // aliases qkv1 (qkv1 dead after k_dw)
    float*  outp  = (float*)d_out;

    hipMemsetAsync(ws + OFF_SSQ, 0, 12288 + 294912, stream);

    k_kv<<<12, 256, 0, stream>>>(prior, w_kernel, kv);
    k_wcast<<<432, 256, 0, stream>>>(w_qkv, Wb);
    k_xt<<<dim3(128, 8), 256, 0, stream>>>(x, kv, xt);
    k_qkv<<<dim3(9, 128, 8), 256, 0, stream>>>(xt, Wb, qkv1);
    k_dw<<<9216, 256, 0, stream>>>(qkv1, w_dw, qkv2, ssq);
    k_vt<<<dim3(128, 8), 256, 0, stream>>>(qkv2, vt);
    k_sdot<<<dim3(32, 4, 8), 256, 0, stream>>>(qkv2, S);
    k_soft<<<32, 256, 0, stream>>>(S, ssq, temp, w_proj, M);
    k_out<<<dim3(3, 128, 8), 256, 0, stream>>>(M, vt, outp);
}

// Round 4
// 292.001 us; speedup vs baseline: 1.3260x; 1.3260x over previous
//
#include <hip/hip_runtime.h>
#include <hip/hip_bf16.h>
#include <stdint.h>

typedef float f32x4 __attribute__((ext_vector_type(4)));
typedef __bf16 bf16x8 __attribute__((ext_vector_type(8)));
typedef __bf16 bf16x2 __attribute__((ext_vector_type(2)));

#define NB 8
#define NC 192
#define NO 576
#define NH 128
#define NWID 128
#define NSP 16384
#define NHEADS 4
#define NCH 48

// workspace layout (bytes)
#define OFF_KV    0u
#define OFF_SSQ   12288u
#define OFF_S     24576u        // 294912 B
#define OFF_WB    319488u       // 221184 B
#define OFF_M     540672u       // 589824 B
#define OFF_XT    1130496u      // xt: 50331648 B; qkv2 aliases (xt dead by then): 150994944 B
#define OFF_QKV1  152125440u    // qkv1: 150994944 B; vT aliases (qkv1 dead after k_dw): 50331648 B

// async global->LDS DMA, 16B per lane; LDS dest is wave-uniform base + lane*16
__device__ __forceinline__ void g2l16(const void* g, void* l) {
    __builtin_amdgcn_global_load_lds((const __attribute__((address_space(1))) void*)g,
                                     (__attribute__((address_space(3))) void*)l, 16, 0, 0);
}

// ---------------- kernel 1: kv = prior @ w_kernel^T  (8 x 384) ----------------
__global__ void k_kv(const float* __restrict__ prior, const float* __restrict__ w_kernel,
                     float* __restrict__ kv) {
    int t = blockIdx.x * 256 + threadIdx.x;
    if (t >= NB * 384) return;
    int b = t / 384, j = t % 384;
    const float* p = prior + b * NC;
    const float* wk = w_kernel + j * NC;
    float s = 0.f;
    for (int f = 0; f < NC; ++f) s += p[f] * wk[f];
    kv[t] = s;
}

// ---------------- kernel 2: cast w_qkv -> bf16 ----------------
__global__ void k_wcast(const float* __restrict__ w_qkv, __bf16* __restrict__ Wb) {
    int t = blockIdx.x * 256 + threadIdx.x;
    if (t < NO * NC) Wb[t] = (__bf16)w_qkv[t];
}

// ---------------- kernel 3: x~ = x*kv1 + kv2, transposed to [b][n][c] bf16 ----------------
__global__ __launch_bounds__(256) void k_xt(const float* __restrict__ x, const float* __restrict__ kv,
                                            __bf16* __restrict__ xt) {
    int b = blockIdx.y;
    int n0 = blockIdx.x * 128;
    __shared__ __align__(16) __bf16 lds[128 * 192];
    int t = threadIdx.x;
    for (int p = 0; p < 24; ++p) {
        int id = p * 256 + t;
        int c = id >> 5, n4 = (id & 31) << 2;
        f32x4 v = *reinterpret_cast<const f32x4*>(x + (size_t)(b * NC + c) * NSP + n0 + n4);
        float k1 = kv[b * 384 + c], k2 = kv[b * 384 + 192 + c];
        int chi = (c >> 3) ^ ((n4 >> 2) & 7);
        int base = chi * 16 + (c & 7) * 2;
#pragma unroll
        for (int j = 0; j < 4; ++j)
            *reinterpret_cast<__bf16*>((char*)lds + (n4 + j) * 384 + base) = (__bf16)(v[j] * k1 + k2);
    }
    __syncthreads();
    for (int p = 0; p < 12; ++p) {
        int id = p * 256 + t;
        int n = id / 24, k = id % 24;
        bf16x8 r = *reinterpret_cast<const bf16x8*>((char*)lds + n * 384 + ((k ^ ((n >> 2) & 7)) << 4));
        *reinterpret_cast<bf16x8*>(xt + (size_t)(b * NSP + n0 + n) * NC + k * 8) = r;
    }
}

// ---------------- kernel 4: qkv GEMM, global_load_lds staged, swizzled ----------------
// B tile (xt) 128x192 bf16 = 48KB at lds[0]; A tile (Wb) 64x192 = 24KB at lds[49152].
// LDS slot (r, c) holds global chunk (c ^ (r&7)); read side applies same XOR.
__global__ __launch_bounds__(256, 2) void k_qkv(const __bf16* __restrict__ xt, const __bf16* __restrict__ Wb,
                                                __bf16* __restrict__ qkv1) {
    __shared__ __align__(16) char lds[73728];
    int b = blockIdx.z, o0 = blockIdx.x * 64, n0 = blockIdx.y * 128;
    int t = threadIdx.x;
    const __bf16* bsrc = xt + (size_t)(b * NSP + n0) * NC;
    const __bf16* asrc = Wb + (size_t)o0 * NC;
#pragma unroll
    for (int i = 0; i < 12; ++i) {
        int s = i * 256 + t;
        int r = s / 24, c = s % 24, g = c ^ (r & 7);
        g2l16(bsrc + (size_t)r * NC + g * 8, lds + s * 16);
    }
#pragma unroll
    for (int i = 0; i < 6; ++i) {
        int s = i * 256 + t;
        int r = s / 24, c = s % 24, g = c ^ (r & 7);
        g2l16(asrc + (size_t)r * NC + g * 8, lds + 49152 + s * 16);
    }
    asm volatile("s_waitcnt vmcnt(0)" ::: "memory");
    __syncthreads();
    int w = t >> 6, l = t & 63, lr = l & 15, lg = l >> 4;
    f32x4 acc[4][2] = {};
#pragma unroll
    for (int ks = 0; ks < 6; ++ks) {
        int c16 = ks * 4 + lg;
        bf16x8 a[4], bb[2];
#pragma unroll
        for (int mf = 0; mf < 4; ++mf) {
            int r = mf * 16 + lr;
            a[mf] = *reinterpret_cast<const bf16x8*>(lds + 49152 + r * 384 + ((c16 ^ (r & 7)) << 4));
        }
#pragma unroll
        for (int nf = 0; nf < 2; ++nf) {
            int r = w * 32 + nf * 16 + lr;
            bb[nf] = *reinterpret_cast<const bf16x8*>(lds + r * 384 + ((c16 ^ (r & 7)) << 4));
        }
#pragma unroll
        for (int mf = 0; mf < 4; ++mf)
#pragma unroll
            for (int nf = 0; nf < 2; ++nf)
                acc[mf][nf] = __builtin_amdgcn_mfma_f32_16x16x32_bf16(a[mf], bb[nf], acc[mf][nf], 0, 0, 0);
    }
#pragma unroll
    for (int mf = 0; mf < 4; ++mf)
#pragma unroll
        for (int r = 0; r < 4; ++r) {
            int orow = o0 + mf * 16 + lg * 4 + r;
#pragma unroll
            for (int nf = 0; nf < 2; ++nf)
                qkv1[(size_t)(b * NO + orow) * NSP + n0 + w * 32 + nf * 16 + lr] = (__bf16)acc[mf][nf][r];
        }
}

// ---------------- kernel 5: depthwise 3x3 conv + sumsq(q,k), register-rolling ----------------
__global__ __launch_bounds__(256) void k_dw(const __bf16* __restrict__ qkv1, const float* __restrict__ w_dw,
                                            __bf16* __restrict__ qkv2, float* __restrict__ ssq) {
    int task = blockIdx.x * 4 + (threadIdx.x >> 6);
    int l = threadIdx.x & 63;
    int strip = task & 7;
    int bo = task >> 3;
    int o = bo % NO, b = bo / NO;
    const __bf16* src = qkv1 + (size_t)bo * NSP;
    __bf16* dst = qkv2 + (size_t)bo * NSP;
    float wd[9];
#pragma unroll
    for (int i = 0; i < 9; ++i) wd[i] = w_dw[o * 9 + i];
    int ys = strip * 16;
    float a0, b0, L0, R0, a1, b1, L1, R1, a2, b2, L2, R2;

#define LOADROW(Y, A, B, L_, R_) {                                            \
        bf16x2 p = {};                                                        \
        int y_ = (Y);                                                         \
        if (y_ >= 0 && y_ < NH) p = *reinterpret_cast<const bf16x2*>(src + y_ * NWID + 2 * l); \
        A = (float)p[0]; B = (float)p[1];                                     \
        L_ = __shfl(B, l - 1); R_ = __shfl(A, l + 1);                         \
        if (l == 0) L_ = 0.f;                                                 \
        if (l == 63) R_ = 0.f; }

    LOADROW(ys - 1, a0, b0, L0, R0)
    LOADROW(ys,     a1, b1, L1, R1)
    float ss = 0.f;
    bool qk = (o < 384);
#pragma unroll 4
    for (int i = 0; i < 16; ++i) {
        LOADROW(ys + i + 1, a2, b2, L2, R2)
        float oa = L0 * wd[0] + a0 * wd[1] + b0 * wd[2]
                 + L1 * wd[3] + a1 * wd[4] + b1 * wd[5]
                 + L2 * wd[6] + a2 * wd[7] + b2 * wd[8];
        float ob = a0 * wd[0] + b0 * wd[1] + R0 * wd[2]
                 + a1 * wd[3] + b1 * wd[4] + R1 * wd[5]
                 + a2 * wd[6] + b2 * wd[7] + R2 * wd[8];
        bf16x2 ov; ov[0] = (__bf16)oa; ov[1] = (__bf16)ob;
        *reinterpret_cast<bf16x2*>(dst + (ys + i) * NWID + 2 * l) = ov;
        if (qk) { float fa = (float)ov[0], fb = (float)ov[1]; ss += fa * fa + fb * fb; }
        a0 = a1; b0 = b1; L0 = L1; R0 = R1;
        a1 = a2; b1 = b2; L1 = L2; R1 = R2;
    }
#undef LOADROW
    if (qk) {
        for (int off = 32; off > 0; off >>= 1) ss += __shfl_down(ss, off);
        if (l == 0) atomicAdd(&ssq[b * 384 + o], ss);
    }
}

// ---------------- kernel 6: transpose v -> vT [b][n][c] (aliases dead qkv1) ----------------
__global__ __launch_bounds__(256) void k_vt(const __bf16* __restrict__ qkv2, __bf16* __restrict__ vt) {
    int b = blockIdx.y;
    int n0 = blockIdx.x * 128;
    __shared__ __align__(16) __bf16 lds[128 * 192];
    int t = threadIdx.x;
    for (int p = 0; p < 12; ++p) {
        int id = p * 256 + t;
        int c = id >> 4, n8 = (id & 15) << 3;
        bf16x8 v = *reinterpret_cast<const bf16x8*>(qkv2 + (size_t)(b * NO + 384 + c) * NSP + n0 + n8);
        int chi = (c >> 3) ^ ((n8 >> 3) & 7);
        int base = chi * 16 + (c & 7) * 2;
#pragma unroll
        for (int j = 0; j < 8; ++j)
            *reinterpret_cast<__bf16*>((char*)lds + (n8 + j) * 384 + base) = v[j];
    }
    __syncthreads();
    for (int p = 0; p < 12; ++p) {
        int id = p * 256 + t;
        int n = id / 24, k = id % 24;
        bf16x8 r = *reinterpret_cast<const bf16x8*>((char*)lds + n * 384 + ((k ^ ((n >> 3) & 7)) << 4));
        *reinterpret_cast<bf16x8*>(vt + (size_t)(b * NSP + n0 + n) * NC + k * 8) = r;
    }
}

// ---------------- kernel 7: Gram dots, staged 2-pass; S += q.k^T over n-chunk 512 ----------------
__global__ __launch_bounds__(256, 3) void k_sdot(const __bf16* __restrict__ qkv2, float* __restrict__ S) {
    __shared__ __align__(16) char lds[49152];
    int b = blockIdx.z, h = blockIdx.y, n0 = blockIdx.x * 512;
    int t = threadIdx.x;
    int w = t >> 6, l = t & 63, lr = l & 15, lg = l >> 4;
    const __bf16* qsrc = qkv2 + (size_t)(b * NO + h * NCH) * NSP + n0;
    const __bf16* ksrc = qkv2 + (size_t)(b * NO + 192 + h * NCH) * NSP + n0;
    f32x4 acc[3][3] = {};
    for (int pass = 0; pass < 2; ++pass) {
        if (pass) __syncthreads();   // all waves done reading previous pass
        int coff = pass * 256;       // column offset within the 512-chunk
#pragma unroll
        for (int i = 0; i < 6; ++i) {
            int s = i * 256 + t;
            int r = s >> 5, c = s & 31, g = c ^ (r & 7);
            g2l16(qsrc + (size_t)r * NSP + coff + g * 8, lds + s * 16);
        }
#pragma unroll
        for (int i = 0; i < 6; ++i) {
            int s = i * 256 + t;
            int r = s >> 5, c = s & 31, g = c ^ (r & 7);
            g2l16(ksrc + (size_t)r * NSP + coff + g * 8, lds + 24576 + s * 16);
        }
        asm volatile("s_waitcnt vmcnt(0)" ::: "memory");
        __syncthreads();
#pragma unroll
        for (int j = 0; j < 2; ++j) {
            int c16 = (w * 2 + j) * 4 + lg;   // 0..31
            bf16x8 a[3], bb[3];
#pragma unroll
            for (int mf = 0; mf < 3; ++mf) {
                int r = mf * 16 + lr;
                a[mf] = *reinterpret_cast<const bf16x8*>(lds + r * 512 + ((c16 ^ (r & 7)) << 4));
            }
#pragma unroll
            for (int nf = 0; nf < 3; ++nf) {
                int r = nf * 16 + lr;
                bb[nf] = *reinterpret_cast<const bf16x8*>(lds + 24576 + r * 512 + ((c16 ^ (r & 7)) << 4));
            }
#pragma unroll
            for (int mf = 0; mf < 3; ++mf)
#pragma unroll
                for (int nf = 0; nf < 3; ++nf)
                    acc[mf][nf] = __builtin_amdgcn_mfma_f32_16x16x32_bf16(a[mf], bb[nf], acc[mf][nf], 0, 0, 0);
        }
    }
    __syncthreads();                 // before aliasing stage LDS as reduction buffer
    float* red = (float*)lds;        // [4][48][49] = 37632 B
#pragma unroll
    for (int mf = 0; mf < 3; ++mf)
#pragma unroll
        for (int nf = 0; nf < 3; ++nf)
#pragma unroll
            for (int r = 0; r < 4; ++r) {
                int c = mf * 16 + lg * 4 + r, d = nf * 16 + lr;
                red[(w * 48 + c) * 49 + d] = acc[mf][nf][r];
            }
    __syncthreads();
    float* Sb = S + (size_t)(b * NHEADS + h) * NCH * NCH;
    for (int i = 0; i < 9; ++i) {
        int idx = t + i * 256;
        int c = idx / 48, d = idx % 48;
        float s = red[c * 49 + d] + red[(48 + c) * 49 + d] + red[(96 + c) * 49 + d] + red[(144 + c) * 49 + d];
        atomicAdd(&Sb[c * 48 + d], s);
    }
}

// ---------------- kernel 8: normalize + softmax + fold proj ----------------
__global__ __launch_bounds__(256) void k_soft(const float* __restrict__ S, const float* __restrict__ ssq,
                                              const float* __restrict__ temp, const float* __restrict__ w_proj,
                                              __bf16* __restrict__ M) {
    int b = blockIdx.x / NHEADS, h = blockIdx.x % NHEADS;
    int tid = threadIdx.x;
    __shared__ float attn[48][48];
    __shared__ float inv[96];
    if (tid < 96) {
        int c = tid % 48;
        int isK = tid / 48;
        float v = ssq[b * 384 + isK * 192 + h * NCH + c];
        float nrm = fmaxf(sqrtf(v), 1e-12f);
        inv[tid] = 1.f / nrm;
    }
    __syncthreads();
    float tp = temp[h];
    const float* Sb = S + (size_t)(b * NHEADS + h) * NCH * NCH;
    for (int i = 0; i < 9; ++i) {
        int idx = tid + i * 256;
        int c = idx / 48, d = idx % 48;
        attn[c][d] = Sb[c * 48 + d] * inv[c] * inv[48 + d] * tp;
    }
    __syncthreads();
    if (tid < 48) {
        float m = -1e30f;
        for (int d = 0; d < 48; ++d) m = fmaxf(m, attn[tid][d]);
        float sum = 0.f;
        for (int d = 0; d < 48; ++d) { float e = __expf(attn[tid][d] - m); attn[tid][d] = e; sum += e; }
        float r = 1.f / sum;
        for (int d = 0; d < 48; ++d) attn[tid][d] *= r;
    }
    __syncthreads();
    for (int i = 0; i < 36; ++i) {
        int idx = tid + i * 256;
        int oo = idx / 48, d = idx % 48;
        const float* wp = w_proj + oo * NC + h * NCH;
        float s = 0.f;
        for (int c = 0; c < 48; ++c) s += wp[c] * attn[c][d];
        M[(size_t)(b * NC + oo) * NC + h * NCH + d] = (__bf16)s;
    }
}

// ---------------- kernel 9: final GEMM, global_load_lds staged, swizzled ----------------
__global__ __launch_bounds__(256, 2) void k_out(const __bf16* __restrict__ Mw, const __bf16* __restrict__ vt,
                                                float* __restrict__ outp) {
    __shared__ __align__(16) char lds[73728];
    int b = blockIdx.z, o0 = blockIdx.x * 64, n0 = blockIdx.y * 128;
    int t = threadIdx.x;
    const __bf16* bsrc = vt + (size_t)(b * NSP + n0) * NC;
    const __bf16* asrc = Mw + (size_t)(b * NC + o0) * NC;
#pragma unroll
    for (int i = 0; i < 12; ++i) {
        int s = i * 256 + t;
        int r = s / 24, c = s % 24, g = c ^ (r & 7);
        g2l16(bsrc + (size_t)r * NC + g * 8, lds + s * 16);
    }
#pragma unroll
    for (int i = 0; i < 6; ++i) {
        int s = i * 256 + t;
        int r = s / 24, c = s % 24, g = c ^ (r & 7);
        g2l16(asrc + (size_t)r * NC + g * 8, lds + 49152 + s * 16);
    }
    asm volatile("s_waitcnt vmcnt(0)" ::: "memory");
    __syncthreads();
    int w = t >> 6, l = t & 63, lr = l & 15, lg = l >> 4;
    f32x4 acc[4][2] = {};
#pragma unroll
    for (int ks = 0; ks < 6; ++ks) {
        int c16 = ks * 4 + lg;
        bf16x8 a[4], bb[2];
#pragma unroll
        for (int mf = 0; mf < 4; ++mf) {
            int r = mf * 16 + lr;
            a[mf] = *reinterpret_cast<const bf16x8*>(lds + 49152 + r * 384 + ((c16 ^ (r & 7)) << 4));
        }
#pragma unroll
        for (int nf = 0; nf < 2; ++nf) {
            int r = w * 32 + nf * 16 + lr;
            bb[nf] = *reinterpret_cast<const bf16x8*>(lds + r * 384 + ((c16 ^ (r & 7)) << 4));
        }
#pragma unroll
        for (int mf = 0; mf < 4; ++mf)
#pragma unroll
            for (int nf = 0; nf < 2; ++nf)
                acc[mf][nf] = __builtin_amdgcn_mfma_f32_16x16x32_bf16(a[mf], bb[nf], acc[mf][nf], 0, 0, 0);
    }
#pragma unroll
    for (int mf = 0; mf < 4; ++mf)
#pragma unroll
        for (int r = 0; r < 4; ++r) {
            int orow = o0 + mf * 16 + lg * 4 + r;
#pragma unroll
            for (int nf = 0; nf < 2; ++nf)
                outp[(size_t)(b * NC + orow) * NSP + n0 + w * 32 + nf * 16 + lr] = acc[mf][nf][r];
        }
}

extern "C" void kernel_launch(void* const* d_in, const int* in_sizes, int n_in,
                              void* d_out, int out_size, void* d_ws, size_t ws_size,
                              hipStream_t stream) {
    const float* x        = (const float*)d_in[0];
    const float* prior    = (const float*)d_in[1];
    const float* w_qkv    = (const float*)d_in[2];
    const float* w_dw     = (const float*)d_in[3];
    const float* w_proj   = (const float*)d_in[4];
    const float* w_kernel = (const float*)d_in[5];
    const float* temp     = (const float*)d_in[6];
    char* ws = (char*)d_ws;
    float*  kv    = (float*)(ws + OFF_KV);
    float*  ssq   = (float*)(ws + OFF_SSQ);
    float*  S     = (float*)(ws + OFF_S);
    __bf16* Wb    = (__bf16*)(ws + OFF_WB);
    __bf16* M     = (__bf16*)(ws + OFF_M);
    __bf16* xt    = (__bf16*)(ws + OFF_XT);
    __bf16* qkv2  = (__bf16*)(ws + OFF_XT);    // aliases xt (xt dead after k_qkv)
    __bf16* qkv1  = (__bf16*)(ws + OFF_QKV1);
    __bf16* vt    = (__bf16*)(ws + OFF_QKV1);  // aliases qkv1 (qkv1 dead after k_dw)
    float*  outp  = (float*)d_out;

    hipMemsetAsync(ws + OFF_SSQ, 0, 12288 + 294912, stream);

    k_kv<<<12, 256, 0, stream>>>(prior, w_kernel, kv);
    k_wcast<<<432, 256, 0, stream>>>(w_qkv, Wb);
    k_xt<<<dim3(128, 8), 256, 0, stream>>>(x, kv, xt);
    k_qkv<<<dim3(9, 128, 8), 256, 0, stream>>>(xt, Wb, qkv1);
    k_dw<<<9216, 256, 0, stream>>>(qkv1, w_dw, qkv2, ssq);
    k_vt<<<dim3(128, 8), 256, 0, stream>>>(qkv2, vt);
    k_sdot<<<dim3(32, 4, 8), 256, 0, stream>>>(qkv2, S);
    k_soft<<<32, 256, 0, stream>>>(S, ssq, temp, w_proj, M);
    k_out<<<dim3(3, 128, 8), 256, 0, stream>>>(M, vt, outp);
}

// Round 5
// 251.696 us; speedup vs baseline: 1.5383x; 1.1601x over previous
//
#include <hip/hip_runtime.h>
#include <hip/hip_bf16.h>
#include <stdint.h>

typedef float f32x4 __attribute__((ext_vector_type(4)));
typedef __bf16 bf16x8 __attribute__((ext_vector_type(8)));
typedef __bf16 bf16x2 __attribute__((ext_vector_type(2)));

#define NB 8
#define NC 192
#define NO 576
#define NH 128
#define NWID 128
#define NSP 16384
#define NHEADS 4
#define NCH 48

// workspace layout (bytes)
#define OFF_KV    0u
#define OFF_SSQ   12288u
#define OFF_S     24576u        // 294912 B
#define OFF_WB    319488u       // 221184 B
#define OFF_M     540672u       // 589824 B
#define OFF_XT    1130496u      // xt: 50331648 B; qkv2 aliases (xt dead by then): 150994944 B
#define OFF_QKV1  152125440u    // qkv1: 150994944 B; vT aliases (qkv1 dead after k_dw): 50331648 B

// async global->LDS DMA, 16B per lane; LDS dest is wave-uniform base + lane*16
__device__ __forceinline__ void g2l16(const void* g, void* l) {
    __builtin_amdgcn_global_load_lds((const __attribute__((address_space(1))) void*)g,
                                     (__attribute__((address_space(3))) void*)l, 16, 0, 0);
}

// ---------------- kernel 1: kv = prior @ w_kernel^T  (8 x 384) ----------------
__global__ void k_kv(const float* __restrict__ prior, const float* __restrict__ w_kernel,
                     float* __restrict__ kv) {
    int t = blockIdx.x * 256 + threadIdx.x;
    if (t >= NB * 384) return;
    int b = t / 384, j = t % 384;
    const float* p = prior + b * NC;
    const float* wk = w_kernel + j * NC;
    float s = 0.f;
    for (int f = 0; f < NC; ++f) s += p[f] * wk[f];
    kv[t] = s;
}

// ---------------- kernel 2: cast w_qkv -> bf16 ----------------
__global__ void k_wcast(const float* __restrict__ w_qkv, __bf16* __restrict__ Wb) {
    int t = blockIdx.x * 256 + threadIdx.x;
    if (t < NO * NC) Wb[t] = (__bf16)w_qkv[t];
}

// ---------------- kernel 3: x~ = x*kv1 + kv2, transposed to [b][n][c] bf16 ----------------
__global__ __launch_bounds__(256) void k_xt(const float* __restrict__ x, const float* __restrict__ kv,
                                            __bf16* __restrict__ xt) {
    int b = blockIdx.y;
    int n0 = blockIdx.x * 128;
    __shared__ __align__(16) __bf16 lds[128 * 192];
    int t = threadIdx.x;
    for (int p = 0; p < 24; ++p) {
        int id = p * 256 + t;
        int c = id >> 5, n4 = (id & 31) << 2;
        f32x4 v = *reinterpret_cast<const f32x4*>(x + (size_t)(b * NC + c) * NSP + n0 + n4);
        float k1 = kv[b * 384 + c], k2 = kv[b * 384 + 192 + c];
        int chi = (c >> 3) ^ ((n4 >> 2) & 7);
        int base = chi * 16 + (c & 7) * 2;
#pragma unroll
        for (int j = 0; j < 4; ++j)
            *reinterpret_cast<__bf16*>((char*)lds + (n4 + j) * 384 + base) = (__bf16)(v[j] * k1 + k2);
    }
    __syncthreads();
    for (int p = 0; p < 12; ++p) {
        int id = p * 256 + t;
        int n = id / 24, k = id % 24;
        bf16x8 r = *reinterpret_cast<const bf16x8*>((char*)lds + n * 384 + ((k ^ ((n >> 2) & 7)) << 4));
        *reinterpret_cast<bf16x8*>(xt + (size_t)(b * NSP + n0 + n) * NC + k * 8) = r;
    }
}

// ---------------- kernel 4: qkv GEMM, B staged once, 9 A-tiles looped ----------------
// B tile (xt) 128x192 bf16 = 48KB at lds[0]; A tile (Wb) 64x192 = 24KB at lds[49152].
// LDS slot (r, c) holds global chunk (c ^ (r&7)); read side applies same XOR.
__global__ __launch_bounds__(256, 2) void k_qkv(const __bf16* __restrict__ xt, const __bf16* __restrict__ Wb,
                                                __bf16* __restrict__ qkv1) {
    __shared__ __align__(16) char lds[73728];
    int b = blockIdx.y, n0 = blockIdx.x * 128;
    int t = threadIdx.x;
    const __bf16* bsrc = xt + (size_t)(b * NSP + n0) * NC;
#pragma unroll
    for (int i = 0; i < 12; ++i) {
        int s = i * 256 + t;
        int r = s / 24, c = s % 24, g = c ^ (r & 7);
        g2l16(bsrc + (size_t)r * NC + g * 8, lds + s * 16);
    }
#pragma unroll
    for (int i = 0; i < 6; ++i) {
        int s = i * 256 + t;
        int r = s / 24, c = s % 24, g = c ^ (r & 7);
        g2l16(Wb + (size_t)r * NC + g * 8, lds + 49152 + s * 16);
    }
    asm volatile("s_waitcnt vmcnt(0)" ::: "memory");
    __syncthreads();
    int w = t >> 6, l = t & 63, lr = l & 15, lg = l >> 4;
    // hoist B fragments into registers (read LDS B once)
    bf16x8 bgf[6][2];
#pragma unroll
    for (int ks = 0; ks < 6; ++ks) {
        int c16 = ks * 4 + lg;
#pragma unroll
        for (int nf = 0; nf < 2; ++nf) {
            int r = w * 32 + nf * 16 + lr;
            bgf[ks][nf] = *reinterpret_cast<const bf16x8*>(lds + r * 384 + ((c16 ^ (r & 7)) << 4));
        }
    }
    for (int ot = 0; ot < 9; ++ot) {
        f32x4 acc[4][2] = {};
#pragma unroll
        for (int ks = 0; ks < 6; ++ks) {
            int c16 = ks * 4 + lg;
            bf16x8 a[4];
#pragma unroll
            for (int mf = 0; mf < 4; ++mf) {
                int r = mf * 16 + lr;
                a[mf] = *reinterpret_cast<const bf16x8*>(lds + 49152 + r * 384 + ((c16 ^ (r & 7)) << 4));
            }
#pragma unroll
            for (int mf = 0; mf < 4; ++mf)
#pragma unroll
                for (int nf = 0; nf < 2; ++nf)
                    acc[mf][nf] = __builtin_amdgcn_mfma_f32_16x16x32_bf16(a[mf], bgf[ks][nf], acc[mf][nf], 0, 0, 0);
        }
        __syncthreads();              // all waves done reading A(ot)
        if (ot < 8) {
            const __bf16* asrc = Wb + (size_t)(ot + 1) * 64 * NC;
#pragma unroll
            for (int i = 0; i < 6; ++i) {
                int s = i * 256 + t;
                int r = s / 24, c = s % 24, g = c ^ (r & 7);
                g2l16(asrc + (size_t)r * NC + g * 8, lds + 49152 + s * 16);
            }
        }
        int o0 = ot * 64;
#pragma unroll
        for (int mf = 0; mf < 4; ++mf)
#pragma unroll
            for (int rr = 0; rr < 4; ++rr) {
                int orow = o0 + mf * 16 + lg * 4 + rr;
#pragma unroll
                for (int nf = 0; nf < 2; ++nf)
                    qkv1[(size_t)(b * NO + orow) * NSP + n0 + w * 32 + nf * 16 + lr] = (__bf16)acc[mf][nf][rr];
            }
        if (ot < 8) {
            // 6 DMAs issued first, then 32 stores: vmcnt(32) => 6 oldest (DMAs) retired
            asm volatile("s_waitcnt vmcnt(32)" ::: "memory");
            __syncthreads();
        }
    }
}

// ---------------- kernel 5: depthwise 3x3 conv + sumsq(q,k), register-rolling ----------------
__global__ __launch_bounds__(256) void k_dw(const __bf16* __restrict__ qkv1, const float* __restrict__ w_dw,
                                            __bf16* __restrict__ qkv2, float* __restrict__ ssq) {
    int task = blockIdx.x * 4 + (threadIdx.x >> 6);
    int l = threadIdx.x & 63;
    int strip = task & 7;
    int bo = task >> 3;
    int o = bo % NO, b = bo / NO;
    const __bf16* src = qkv1 + (size_t)bo * NSP;
    __bf16* dst = qkv2 + (size_t)bo * NSP;
    float wd[9];
#pragma unroll
    for (int i = 0; i < 9; ++i) wd[i] = w_dw[o * 9 + i];
    int ys = strip * 16;
    float a0, b0, L0, R0, a1, b1, L1, R1, a2, b2, L2, R2;

#define LOADROW(Y, A, B, L_, R_) {                                            \
        bf16x2 p = {};                                                        \
        int y_ = (Y);                                                         \
        if (y_ >= 0 && y_ < NH) p = *reinterpret_cast<const bf16x2*>(src + y_ * NWID + 2 * l); \
        A = (float)p[0]; B = (float)p[1];                                     \
        L_ = __shfl(B, l - 1); R_ = __shfl(A, l + 1);                         \
        if (l == 0) L_ = 0.f;                                                 \
        if (l == 63) R_ = 0.f; }

    LOADROW(ys - 1, a0, b0, L0, R0)
    LOADROW(ys,     a1, b1, L1, R1)
    float ss = 0.f;
    bool qk = (o < 384);
#pragma unroll 4
    for (int i = 0; i < 16; ++i) {
        LOADROW(ys + i + 1, a2, b2, L2, R2)
        float oa = L0 * wd[0] + a0 * wd[1] + b0 * wd[2]
                 + L1 * wd[3] + a1 * wd[4] + b1 * wd[5]
                 + L2 * wd[6] + a2 * wd[7] + b2 * wd[8];
        float ob = a0 * wd[0] + b0 * wd[1] + R0 * wd[2]
                 + a1 * wd[3] + b1 * wd[4] + R1 * wd[5]
                 + a2 * wd[6] + b2 * wd[7] + R2 * wd[8];
        bf16x2 ov; ov[0] = (__bf16)oa; ov[1] = (__bf16)ob;
        *reinterpret_cast<bf16x2*>(dst + (ys + i) * NWID + 2 * l) = ov;
        if (qk) { float fa = (float)ov[0], fb = (float)ov[1]; ss += fa * fa + fb * fb; }
        a0 = a1; b0 = b1; L0 = L1; R0 = R1;
        a1 = a2; b1 = b2; L1 = L2; R1 = R2;
    }
#undef LOADROW
    if (qk) {
        for (int off = 32; off > 0; off >>= 1) ss += __shfl_down(ss, off);
        if (l == 0) atomicAdd(&ssq[b * 384 + o], ss);
    }
}

// ---------------- kernel 6: transpose v -> vT [b][n][c] (aliases dead qkv1) ----------------
__global__ __launch_bounds__(256) void k_vt(const __bf16* __restrict__ qkv2, __bf16* __restrict__ vt) {
    int b = blockIdx.y;
    int n0 = blockIdx.x * 128;
    __shared__ __align__(16) __bf16 lds[128 * 192];
    int t = threadIdx.x;
    for (int p = 0; p < 12; ++p) {
        int id = p * 256 + t;
        int c = id >> 4, n8 = (id & 15) << 3;
        bf16x8 v = *reinterpret_cast<const bf16x8*>(qkv2 + (size_t)(b * NO + 384 + c) * NSP + n0 + n8);
        int chi = (c >> 3) ^ ((n8 >> 3) & 7);
        int base = chi * 16 + (c & 7) * 2;
#pragma unroll
        for (int j = 0; j < 8; ++j)
            *reinterpret_cast<__bf16*>((char*)lds + (n8 + j) * 384 + base) = v[j];
    }
    __syncthreads();
    for (int p = 0; p < 12; ++p) {
        int id = p * 256 + t;
        int n = id / 24, k = id % 24;
        bf16x8 r = *reinterpret_cast<const bf16x8*>((char*)lds + n * 384 + ((k ^ ((n >> 3) & 7)) << 4));
        *reinterpret_cast<bf16x8*>(vt + (size_t)(b * NSP + n0 + n) * NC + k * 8) = r;
    }
}

// ---------------- kernel 7: Gram dots, staged 2-pass; S += q.k^T over n-chunk 512 ----------------
__global__ __launch_bounds__(256, 3) void k_sdot(const __bf16* __restrict__ qkv2, float* __restrict__ S) {
    __shared__ __align__(16) char lds[49152];
    int b = blockIdx.z, h = blockIdx.y, n0 = blockIdx.x * 512;
    int t = threadIdx.x;
    int w = t >> 6, l = t & 63, lr = l & 15, lg = l >> 4;
    const __bf16* qsrc = qkv2 + (size_t)(b * NO + h * NCH) * NSP + n0;
    const __bf16* ksrc = qkv2 + (size_t)(b * NO + 192 + h * NCH) * NSP + n0;
    f32x4 acc[3][3] = {};
    for (int pass = 0; pass < 2; ++pass) {
        if (pass) __syncthreads();
        int coff = pass * 256;
#pragma unroll
        for (int i = 0; i < 6; ++i) {
            int s = i * 256 + t;
            int r = s >> 5, c = s & 31, g = c ^ (r & 7);
            g2l16(qsrc + (size_t)r * NSP + coff + g * 8, lds + s * 16);
        }
#pragma unroll
        for (int i = 0; i < 6; ++i) {
            int s = i * 256 + t;
            int r = s >> 5, c = s & 31, g = c ^ (r & 7);
            g2l16(ksrc + (size_t)r * NSP + coff + g * 8, lds + 24576 + s * 16);
        }
        asm volatile("s_waitcnt vmcnt(0)" ::: "memory");
        __syncthreads();
#pragma unroll
        for (int j = 0; j < 2; ++j) {
            int c16 = (w * 2 + j) * 4 + lg;
            bf16x8 a[3], bb[3];
#pragma unroll
            for (int mf = 0; mf < 3; ++mf) {
                int r = mf * 16 + lr;
                a[mf] = *reinterpret_cast<const bf16x8*>(lds + r * 512 + ((c16 ^ (r & 7)) << 4));
            }
#pragma unroll
            for (int nf = 0; nf < 3; ++nf) {
                int r = nf * 16 + lr;
                bb[nf] = *reinterpret_cast<const bf16x8*>(lds + 24576 + r * 512 + ((c16 ^ (r & 7)) << 4));
            }
#pragma unroll
            for (int mf = 0; mf < 3; ++mf)
#pragma unroll
                for (int nf = 0; nf < 3; ++nf)
                    acc[mf][nf] = __builtin_amdgcn_mfma_f32_16x16x32_bf16(a[mf], bb[nf], acc[mf][nf], 0, 0, 0);
        }
    }
    __syncthreads();
    float* red = (float*)lds;
#pragma unroll
    for (int mf = 0; mf < 3; ++mf)
#pragma unroll
        for (int nf = 0; nf < 3; ++nf)
#pragma unroll
            for (int r = 0; r < 4; ++r) {
                int c = mf * 16 + lg * 4 + r, d = nf * 16 + lr;
                red[(w * 48 + c) * 49 + d] = acc[mf][nf][r];
            }
    __syncthreads();
    float* Sb = S + (size_t)(b * NHEADS + h) * NCH * NCH;
    for (int i = 0; i < 9; ++i) {
        int idx = t + i * 256;
        int c = idx / 48, d = idx % 48;
        float s = red[c * 49 + d] + red[(48 + c) * 49 + d] + red[(96 + c) * 49 + d] + red[(144 + c) * 49 + d];
        atomicAdd(&Sb[c * 48 + d], s);
    }
}

// ---------------- kernel 8: normalize + softmax + fold proj ----------------
__global__ __launch_bounds__(256) void k_soft(const float* __restrict__ S, const float* __restrict__ ssq,
                                              const float* __restrict__ temp, const float* __restrict__ w_proj,
                                              __bf16* __restrict__ M) {
    int b = blockIdx.x / NHEADS, h = blockIdx.x % NHEADS;
    int tid = threadIdx.x;
    __shared__ float attn[48][48];
    __shared__ float inv[96];
    if (tid < 96) {
        int c = tid % 48;
        int isK = tid / 48;
        float v = ssq[b * 384 + isK * 192 + h * NCH + c];
        float nrm = fmaxf(sqrtf(v), 1e-12f);
        inv[tid] = 1.f / nrm;
    }
    __syncthreads();
    float tp = temp[h];
    const float* Sb = S + (size_t)(b * NHEADS + h) * NCH * NCH;
    for (int i = 0; i < 9; ++i) {
        int idx = tid + i * 256;
        int c = idx / 48, d = idx % 48;
        attn[c][d] = Sb[c * 48 + d] * inv[c] * inv[48 + d] * tp;
    }
    __syncthreads();
    if (tid < 48) {
        float m = -1e30f;
        for (int d = 0; d < 48; ++d) m = fmaxf(m, attn[tid][d]);
        float sum = 0.f;
        for (int d = 0; d < 48; ++d) { float e = __expf(attn[tid][d] - m); attn[tid][d] = e; sum += e; }
        float r = 1.f / sum;
        for (int d = 0; d < 48; ++d) attn[tid][d] *= r;
    }
    __syncthreads();
    for (int i = 0; i < 36; ++i) {
        int idx = tid + i * 256;
        int oo = idx / 48, d = idx % 48;
        const float* wp = w_proj + oo * NC + h * NCH;
        float s = 0.f;
        for (int c = 0; c < 48; ++c) s += wp[c] * attn[c][d];
        M[(size_t)(b * NC + oo) * NC + h * NCH + d] = (__bf16)s;
    }
}

// ---------------- kernel 9: final GEMM, B staged once, 3 A-tiles looped ----------------
__global__ __launch_bounds__(256, 2) void k_out(const __bf16* __restrict__ Mw, const __bf16* __restrict__ vt,
                                                float* __restrict__ outp) {
    __shared__ __align__(16) char lds[73728];
    int b = blockIdx.y, n0 = blockIdx.x * 128;
    int t = threadIdx.x;
    const __bf16* bsrc = vt + (size_t)(b * NSP + n0) * NC;
#pragma unroll
    for (int i = 0; i < 12; ++i) {
        int s = i * 256 + t;
        int r = s / 24, c = s % 24, g = c ^ (r & 7);
        g2l16(bsrc + (size_t)r * NC + g * 8, lds + s * 16);
    }
    const __bf16* asrc0 = Mw + (size_t)(b * NC) * NC;
#pragma unroll
    for (int i = 0; i < 6; ++i) {
        int s = i * 256 + t;
        int r = s / 24, c = s % 24, g = c ^ (r & 7);
        g2l16(asrc0 + (size_t)r * NC + g * 8, lds + 49152 + s * 16);
    }
    asm volatile("s_waitcnt vmcnt(0)" ::: "memory");
    __syncthreads();
    int w = t >> 6, l = t & 63, lr = l & 15, lg = l >> 4;
    bf16x8 bgf[6][2];
#pragma unroll
    for (int ks = 0; ks < 6; ++ks) {
        int c16 = ks * 4 + lg;
#pragma unroll
        for (int nf = 0; nf < 2; ++nf) {
            int r = w * 32 + nf * 16 + lr;
            bgf[ks][nf] = *reinterpret_cast<const bf16x8*>(lds + r * 384 + ((c16 ^ (r & 7)) << 4));
        }
    }
    for (int ot = 0; ot < 3; ++ot) {
        f32x4 acc[4][2] = {};
#pragma unroll
        for (int ks = 0; ks < 6; ++ks) {
            int c16 = ks * 4 + lg;
            bf16x8 a[4];
#pragma unroll
            for (int mf = 0; mf < 4; ++mf) {
                int r = mf * 16 + lr;
                a[mf] = *reinterpret_cast<const bf16x8*>(lds + 49152 + r * 384 + ((c16 ^ (r & 7)) << 4));
            }
#pragma unroll
            for (int mf = 0; mf < 4; ++mf)
#pragma unroll
                for (int nf = 0; nf < 2; ++nf)
                    acc[mf][nf] = __builtin_amdgcn_mfma_f32_16x16x32_bf16(a[mf], bgf[ks][nf], acc[mf][nf], 0, 0, 0);
        }
        __syncthreads();
        if (ot < 2) {
            const __bf16* asrc = Mw + (size_t)(b * NC + (ot + 1) * 64) * NC;
#pragma unroll
            for (int i = 0; i < 6; ++i) {
                int s = i * 256 + t;
                int r = s / 24, c = s % 24, g = c ^ (r & 7);
                g2l16(asrc + (size_t)r * NC + g * 8, lds + 49152 + s * 16);
            }
        }
        int o0 = ot * 64;
#pragma unroll
        for (int mf = 0; mf < 4; ++mf)
#pragma unroll
            for (int rr = 0; rr < 4; ++rr) {
                int orow = o0 + mf * 16 + lg * 4 + rr;
#pragma unroll
                for (int nf = 0; nf < 2; ++nf)
                    outp[(size_t)(b * NC + orow) * NSP + n0 + w * 32 + nf * 16 + lr] = acc[mf][nf][rr];
            }
        if (ot < 2) {
            asm volatile("s_waitcnt vmcnt(32)" ::: "memory");
            __syncthreads();
        }
    }
}

extern "C" void kernel_launch(void* const* d_in, const int* in_sizes, int n_in,
                              void* d_out, int out_size, void* d_ws, size_t ws_size,
                              hipStream_t stream) {
    const float* x        = (const float*)d_in[0];
    const float* prior    = (const float*)d_in[1];
    const float* w_qkv    = (const float*)d_in[2];
    const float* w_dw     = (const float*)d_in[3];
    const float* w_proj   = (const float*)d_in[4];
    const float* w_kernel = (const float*)d_in[5];
    const float* temp     = (const float*)d_in[6];
    char* ws = (char*)d_ws;
    float*  kv    = (float*)(ws + OFF_KV);
    float*  ssq   = (float*)(ws + OFF_SSQ);
    float*  S     = (float*)(ws + OFF_S);
    __bf16* Wb    = (__bf16*)(ws + OFF_WB);
    __bf16* M     = (__bf16*)(ws + OFF_M);
    __bf16* xt    = (__bf16*)(ws + OFF_XT);
    __bf16* qkv2  = (__bf16*)(ws + OFF_XT);    // aliases xt (xt dead after k_qkv)
    __bf16* qkv1  = (__bf16*)(ws + OFF_QKV1);
    __bf16* vt    = (__bf16*)(ws + OFF_QKV1);  // aliases qkv1 (qkv1 dead after k_dw)
    float*  outp  = (float*)d_out;

    hipMemsetAsync(ws + OFF_SSQ, 0, 12288 + 294912, stream);

    k_kv<<<12, 256, 0, stream>>>(prior, w_kernel, kv);
    k_wcast<<<432, 256, 0, stream>>>(w_qkv, Wb);
    k_xt<<<dim3(128, 8), 256, 0, stream>>>(x, kv, xt);
    k_qkv<<<dim3(128, 8), 256, 0, stream>>>(xt, Wb, qkv1);
    k_dw<<<9216, 256, 0, stream>>>(qkv1, w_dw, qkv2, ssq);
    k_vt<<<dim3(128, 8), 256, 0, stream>>>(qkv2, vt);
    k_sdot<<<dim3(32, 4, 8), 256, 0, stream>>>(qkv2, S);
    k_soft<<<32, 256, 0, stream>>>(S, ssq, temp, w_proj, M);
    k_out<<<dim3(128, 8), 256, 0, stream>>>(M, vt, outp);
}

// Round 6
// 235.639 us; speedup vs baseline: 1.6432x; 1.0681x over previous
//
#include <hip/hip_runtime.h>
#include <hip/hip_bf16.h>
#include <stdint.h>

typedef float f32x4 __attribute__((ext_vector_type(4)));
typedef __bf16 bf16x8 __attribute__((ext_vector_type(8)));
typedef __bf16 bf16x2 __attribute__((ext_vector_type(2)));

#define NB 8
#define NC 192
#define NO 576
#define NH 128
#define NWID 128
#define NSP 16384
#define NHEADS 4
#define NCH 48

// workspace layout (bytes)
#define OFF_KV    0u
#define OFF_SSQ   12288u        // ssq 12288 B + S 294912 B contiguous (zeroed by k_kv)
#define OFF_S     24576u
#define OFF_WB    319488u       // 221184 B
#define OFF_M     540672u       // 589824 B
#define OFF_QKV2  1130496u      // 150994944 B
#define OFF_QKV1  152125440u    // 150994944 B

// async global->LDS DMA, 16B per lane; LDS dest is wave-uniform base + lane*16
__device__ __forceinline__ void g2l16(const void* g, void* l) {
    __builtin_amdgcn_global_load_lds((const __attribute__((address_space(1))) void*)g,
                                     (__attribute__((address_space(3))) void*)l, 16, 0, 0);
}

// ---------------- kernel 1: kv = prior @ w_kernel^T (8 x 384); also zeroes ssq+S ----------------
__global__ void k_kv(const float* __restrict__ prior, const float* __restrict__ w_kernel,
                     float* __restrict__ kv, float* __restrict__ zbase) {
    int t = blockIdx.x * 256 + threadIdx.x;
    for (int i = t; i < 76800; i += 3072) zbase[i] = 0.f;   // ssq(3072f) + S(73728f)
    if (t >= NB * 384) return;
    int b = t / 384, j = t % 384;
    const float* p = prior + b * NC;
    const float* wk = w_kernel + j * NC;
    float s = 0.f;
    for (int f = 0; f < NC; ++f) s += p[f] * wk[f];
    kv[t] = s;
}

// ---------------- kernel 2: cast w_qkv -> bf16 ----------------
__global__ void k_wcast(const float* __restrict__ w_qkv, __bf16* __restrict__ Wb) {
    int t = blockIdx.x * 256 + threadIdx.x;
    if (t < NO * NC) Wb[t] = (__bf16)w_qkv[t];
}

// ---------------- kernel 3: qkv GEMM, fused affine+transpose staging, 9 A-tiles looped ----------------
// B tile built in-kernel from x: LDS row n (0..127), 24 chunks of 8c; slot = chunk ^ (n&7).
// A tile (Wb) 64x192 = 24KB at lds[49152] via DMA with pre-swizzled source.
__global__ __launch_bounds__(256, 2) void k_qkv(const float* __restrict__ x, const float* __restrict__ kv,
                                                const __bf16* __restrict__ Wb, __bf16* __restrict__ qkv1) {
    __shared__ __align__(16) char lds[73728];
    int b = blockIdx.y, n0 = blockIdx.x * 128;
    int t = threadIdx.x;
    // A-tile 0 DMA (vmcnt-tracked)
#pragma unroll
    for (int i = 0; i < 6; ++i) {
        int s = i * 256 + t;
        int r = s / 24, c = s % 24, g = c ^ (r & 7);
        g2l16(Wb + (size_t)r * NC + g * 8, lds + 49152 + s * 16);
    }
    // B-tile: read x fp32, affine, pack, swizzled ds_write_b128
    const float* xb = x + (size_t)b * NC * NSP + n0;
    const float* kvb = kv + b * 384;
#pragma unroll 4
    for (int p = 0; p < 12; ++p) {
        int task = p * 256 + t;
        int n = task & 127, ch = task >> 7;
        bf16x8 vv;
#pragma unroll
        for (int j = 0; j < 8; ++j) {
            int c = ch * 8 + j;
            float xv = xb[(size_t)c * NSP + n];
            vv[j] = (__bf16)(xv * kvb[c] + kvb[192 + c]);
        }
        *reinterpret_cast<bf16x8*>(lds + n * 384 + ((ch ^ (n & 7)) << 4)) = vv;
    }
    asm volatile("s_waitcnt vmcnt(0)" ::: "memory");
    __syncthreads();
    int w = t >> 6, l = t & 63, lr = l & 15, lg = l >> 4;
    // hoist B fragments into registers (read LDS B once)
    bf16x8 bgf[6][2];
#pragma unroll
    for (int ks = 0; ks < 6; ++ks) {
        int c16 = ks * 4 + lg;
#pragma unroll
        for (int nf = 0; nf < 2; ++nf) {
            int r = w * 32 + nf * 16 + lr;
            bgf[ks][nf] = *reinterpret_cast<const bf16x8*>(lds + r * 384 + ((c16 ^ (r & 7)) << 4));
        }
    }
    for (int ot = 0; ot < 9; ++ot) {
        f32x4 acc[4][2] = {};
#pragma unroll
        for (int ks = 0; ks < 6; ++ks) {
            int c16 = ks * 4 + lg;
            bf16x8 a[4];
#pragma unroll
            for (int mf = 0; mf < 4; ++mf) {
                int r = mf * 16 + lr;
                a[mf] = *reinterpret_cast<const bf16x8*>(lds + 49152 + r * 384 + ((c16 ^ (r & 7)) << 4));
            }
#pragma unroll
            for (int mf = 0; mf < 4; ++mf)
#pragma unroll
                for (int nf = 0; nf < 2; ++nf)
                    acc[mf][nf] = __builtin_amdgcn_mfma_f32_16x16x32_bf16(a[mf], bgf[ks][nf], acc[mf][nf], 0, 0, 0);
        }
        __syncthreads();              // all waves done reading A(ot)
        if (ot < 8) {
            const __bf16* asrc = Wb + (size_t)(ot + 1) * 64 * NC;
#pragma unroll
            for (int i = 0; i < 6; ++i) {
                int s = i * 256 + t;
                int r = s / 24, c = s % 24, g = c ^ (r & 7);
                g2l16(asrc + (size_t)r * NC + g * 8, lds + 49152 + s * 16);
            }
        }
        int o0 = ot * 64;
#pragma unroll
        for (int mf = 0; mf < 4; ++mf)
#pragma unroll
            for (int rr = 0; rr < 4; ++rr) {
                int orow = o0 + mf * 16 + lg * 4 + rr;
#pragma unroll
                for (int nf = 0; nf < 2; ++nf)
                    qkv1[(size_t)(b * NO + orow) * NSP + n0 + w * 32 + nf * 16 + lr] = (__bf16)acc[mf][nf][rr];
            }
        if (ot < 8) {
            // 6 DMAs issued first, then 32 stores: vmcnt(32) => 6 oldest (DMAs) retired
            asm volatile("s_waitcnt vmcnt(32)" ::: "memory");
            __syncthreads();
        }
    }
}

// ---------------- kernel 4: depthwise 3x3 conv + sumsq(q,k), register-rolling ----------------
__global__ __launch_bounds__(256) void k_dw(const __bf16* __restrict__ qkv1, const float* __restrict__ w_dw,
                                            __bf16* __restrict__ qkv2, float* __restrict__ ssq) {
    int task = blockIdx.x * 4 + (threadIdx.x >> 6);
    int l = threadIdx.x & 63;
    int strip = task & 7;
    int bo = task >> 3;
    int o = bo % NO, b = bo / NO;
    const __bf16* src = qkv1 + (size_t)bo * NSP;
    __bf16* dst = qkv2 + (size_t)bo * NSP;
    float wd[9];
#pragma unroll
    for (int i = 0; i < 9; ++i) wd[i] = w_dw[o * 9 + i];
    int ys = strip * 16;
    float a0, b0, L0, R0, a1, b1, L1, R1, a2, b2, L2, R2;

#define LOADROW(Y, A, B, L_, R_) {                                            \
        bf16x2 p = {};                                                        \
        int y_ = (Y);                                                         \
        if (y_ >= 0 && y_ < NH) p = *reinterpret_cast<const bf16x2*>(src + y_ * NWID + 2 * l); \
        A = (float)p[0]; B = (float)p[1];                                     \
        L_ = __shfl(B, l - 1); R_ = __shfl(A, l + 1);                         \
        if (l == 0) L_ = 0.f;                                                 \
        if (l == 63) R_ = 0.f; }

    LOADROW(ys - 1, a0, b0, L0, R0)
    LOADROW(ys,     a1, b1, L1, R1)
    float ss = 0.f;
    bool qk = (o < 384);
#pragma unroll 4
    for (int i = 0; i < 16; ++i) {
        LOADROW(ys + i + 1, a2, b2, L2, R2)
        float oa = L0 * wd[0] + a0 * wd[1] + b0 * wd[2]
                 + L1 * wd[3] + a1 * wd[4] + b1 * wd[5]
                 + L2 * wd[6] + a2 * wd[7] + b2 * wd[8];
        float ob = a0 * wd[0] + b0 * wd[1] + R0 * wd[2]
                 + a1 * wd[3] + b1 * wd[4] + R1 * wd[5]
                 + a2 * wd[6] + b2 * wd[7] + R2 * wd[8];
        bf16x2 ov; ov[0] = (__bf16)oa; ov[1] = (__bf16)ob;
        *reinterpret_cast<bf16x2*>(dst + (ys + i) * NWID + 2 * l) = ov;
        if (qk) { float fa = (float)ov[0], fb = (float)ov[1]; ss += fa * fa + fb * fb; }
        a0 = a1; b0 = b1; L0 = L1; R0 = R1;
        a1 = a2; b1 = b2; L1 = L2; R1 = R2;
    }
#undef LOADROW
    if (qk) {
        for (int off = 32; off > 0; off >>= 1) ss += __shfl_down(ss, off);
        if (l == 0) atomicAdd(&ssq[b * 384 + o], ss);
    }
}

// ---------------- kernel 5: Gram dots, staged 2-pass; S += q.k^T over n-chunk 512 ----------------
__global__ __launch_bounds__(256, 3) void k_sdot(const __bf16* __restrict__ qkv2, float* __restrict__ S) {
    __shared__ __align__(16) char lds[49152];
    int b = blockIdx.z, h = blockIdx.y, n0 = blockIdx.x * 512;
    int t = threadIdx.x;
    int w = t >> 6, l = t & 63, lr = l & 15, lg = l >> 4;
    const __bf16* qsrc = qkv2 + (size_t)(b * NO + h * NCH) * NSP + n0;
    const __bf16* ksrc = qkv2 + (size_t)(b * NO + 192 + h * NCH) * NSP + n0;
    f32x4 acc[3][3] = {};
    for (int pass = 0; pass < 2; ++pass) {
        if (pass) __syncthreads();
        int coff = pass * 256;
#pragma unroll
        for (int i = 0; i < 6; ++i) {
            int s = i * 256 + t;
            int r = s >> 5, c = s & 31, g = c ^ (r & 7);
            g2l16(qsrc + (size_t)r * NSP + coff + g * 8, lds + s * 16);
        }
#pragma unroll
        for (int i = 0; i < 6; ++i) {
            int s = i * 256 + t;
            int r = s >> 5, c = s & 31, g = c ^ (r & 7);
            g2l16(ksrc + (size_t)r * NSP + coff + g * 8, lds + 24576 + s * 16);
        }
        asm volatile("s_waitcnt vmcnt(0)" ::: "memory");
        __syncthreads();
#pragma unroll
        for (int j = 0; j < 2; ++j) {
            int c16 = (w * 2 + j) * 4 + lg;
            bf16x8 a[3], bb[3];
#pragma unroll
            for (int mf = 0; mf < 3; ++mf) {
                int r = mf * 16 + lr;
                a[mf] = *reinterpret_cast<const bf16x8*>(lds + r * 512 + ((c16 ^ (r & 7)) << 4));
            }
#pragma unroll
            for (int nf = 0; nf < 3; ++nf) {
                int r = nf * 16 + lr;
                bb[nf] = *reinterpret_cast<const bf16x8*>(lds + 24576 + r * 512 + ((c16 ^ (r & 7)) << 4));
            }
#pragma unroll
            for (int mf = 0; mf < 3; ++mf)
#pragma unroll
                for (int nf = 0; nf < 3; ++nf)
                    acc[mf][nf] = __builtin_amdgcn_mfma_f32_16x16x32_bf16(a[mf], bb[nf], acc[mf][nf], 0, 0, 0);
        }
    }
    __syncthreads();
    float* red = (float*)lds;
#pragma unroll
    for (int mf = 0; mf < 3; ++mf)
#pragma unroll
        for (int nf = 0; nf < 3; ++nf)
#pragma unroll
            for (int r = 0; r < 4; ++r) {
                int c = mf * 16 + lg * 4 + r, d = nf * 16 + lr;
                red[(w * 48 + c) * 49 + d] = acc[mf][nf][r];
            }
    __syncthreads();
    float* Sb = S + (size_t)(b * NHEADS + h) * NCH * NCH;
    for (int i = 0; i < 9; ++i) {
        int idx = t + i * 256;
        int c = idx / 48, d = idx % 48;
        float s = red[c * 49 + d] + red[(48 + c) * 49 + d] + red[(96 + c) * 49 + d] + red[(144 + c) * 49 + d];
        atomicAdd(&Sb[c * 48 + d], s);
    }
}

// ---------------- kernel 6: normalize + softmax + fold proj ----------------
__global__ __launch_bounds__(256) void k_soft(const float* __restrict__ S, const float* __restrict__ ssq,
                                              const float* __restrict__ temp, const float* __restrict__ w_proj,
                                              __bf16* __restrict__ M) {
    int b = blockIdx.x / NHEADS, h = blockIdx.x % NHEADS;
    int tid = threadIdx.x;
    __shared__ float attn[48][48];
    __shared__ float inv[96];
    if (tid < 96) {
        int c = tid % 48;
        int isK = tid / 48;
        float v = ssq[b * 384 + isK * 192 + h * NCH + c];
        float nrm = fmaxf(sqrtf(v), 1e-12f);
        inv[tid] = 1.f / nrm;
    }
    __syncthreads();
    float tp = temp[h];
    const float* Sb = S + (size_t)(b * NHEADS + h) * NCH * NCH;
    for (int i = 0; i < 9; ++i) {
        int idx = tid + i * 256;
        int c = idx / 48, d = idx % 48;
        attn[c][d] = Sb[c * 48 + d] * inv[c] * inv[48 + d] * tp;
    }
    __syncthreads();
    if (tid < 48) {
        float m = -1e30f;
        for (int d = 0; d < 48; ++d) m = fmaxf(m, attn[tid][d]);
        float sum = 0.f;
        for (int d = 0; d < 48; ++d) { float e = __expf(attn[tid][d] - m); attn[tid][d] = e; sum += e; }
        float r = 1.f / sum;
        for (int d = 0; d < 48; ++d) attn[tid][d] *= r;
    }
    __syncthreads();
    for (int i = 0; i < 36; ++i) {
        int idx = tid + i * 256;
        int oo = idx / 48, d = idx % 48;
        const float* wp = w_proj + oo * NC + h * NCH;
        float s = 0.f;
        for (int c = 0; c < 48; ++c) s += wp[c] * attn[c][d];
        M[(size_t)(b * NC + oo) * NC + h * NCH + d] = (__bf16)s;
    }
}

// ---------------- kernel 7: final GEMM, fused v-transpose staging, 3 A-tiles looped ----------------
__global__ __launch_bounds__(256, 2) void k_out(const __bf16* __restrict__ Mw, const __bf16* __restrict__ qkv2,
                                                float* __restrict__ outp) {
    __shared__ __align__(16) char lds[73728];
    int b = blockIdx.y, n0 = blockIdx.x * 128;
    int t = threadIdx.x;
    // A-tile 0 DMA
    const __bf16* asrc0 = Mw + (size_t)(b * NC) * NC;
#pragma unroll
    for (int i = 0; i < 6; ++i) {
        int s = i * 256 + t;
        int r = s / 24, c = s % 24, g = c ^ (r & 7);
        g2l16(asrc0 + (size_t)r * NC + g * 8, lds + 49152 + s * 16);
    }
    // B-tile: gather v columns, swizzled ds_write_b128
    const __bf16* vb = qkv2 + (size_t)(b * NO + 384) * NSP + n0;
#pragma unroll 4
    for (int p = 0; p < 12; ++p) {
        int task = p * 256 + t;
        int n = task & 127, ch = task >> 7;
        bf16x8 vv;
#pragma unroll
        for (int j = 0; j < 8; ++j)
            vv[j] = vb[(size_t)(ch * 8 + j) * NSP + n];
        *reinterpret_cast<bf16x8*>(lds + n * 384 + ((ch ^ (n & 7)) << 4)) = vv;
    }
    asm volatile("s_waitcnt vmcnt(0)" ::: "memory");
    __syncthreads();
    int w = t >> 6, l = t & 63, lr = l & 15, lg = l >> 4;
    bf16x8 bgf[6][2];
#pragma unroll
    for (int ks = 0; ks < 6; ++ks) {
        int c16 = ks * 4 + lg;
#pragma unroll
        for (int nf = 0; nf < 2; ++nf) {
            int r = w * 32 + nf * 16 + lr;
            bgf[ks][nf] = *reinterpret_cast<const bf16x8*>(lds + r * 384 + ((c16 ^ (r & 7)) << 4));
        }
    }
    for (int ot = 0; ot < 3; ++ot) {
        f32x4 acc[4][2] = {};
#pragma unroll
        for (int ks = 0; ks < 6; ++ks) {
            int c16 = ks * 4 + lg;
            bf16x8 a[4];
#pragma unroll
            for (int mf = 0; mf < 4; ++mf) {
                int r = mf * 16 + lr;
                a[mf] = *reinterpret_cast<const bf16x8*>(lds + 49152 + r * 384 + ((c16 ^ (r & 7)) << 4));
            }
#pragma unroll
            for (int mf = 0; mf < 4; ++mf)
#pragma unroll
                for (int nf = 0; nf < 2; ++nf)
                    acc[mf][nf] = __builtin_amdgcn_mfma_f32_16x16x32_bf16(a[mf], bgf[ks][nf], acc[mf][nf], 0, 0, 0);
        }
        __syncthreads();
        if (ot < 2) {
            const __bf16* asrc = Mw + (size_t)(b * NC + (ot + 1) * 64) * NC;
#pragma unroll
            for (int i = 0; i < 6; ++i) {
                int s = i * 256 + t;
                int r = s / 24, c = s % 24, g = c ^ (r & 7);
                g2l16(asrc + (size_t)r * NC + g * 8, lds + 49152 + s * 16);
            }
        }
        int o0 = ot * 64;
#pragma unroll
        for (int mf = 0; mf < 4; ++mf)
#pragma unroll
            for (int rr = 0; rr < 4; ++rr) {
                int orow = o0 + mf * 16 + lg * 4 + rr;
#pragma unroll
                for (int nf = 0; nf < 2; ++nf)
                    outp[(size_t)(b * NC + orow) * NSP + n0 + w * 32 + nf * 16 + lr] = acc[mf][nf][rr];
            }
        if (ot < 2) {
            asm volatile("s_waitcnt vmcnt(32)" ::: "memory");
            __syncthreads();
        }
    }
}

extern "C" void kernel_launch(void* const* d_in, const int* in_sizes, int n_in,
                              void* d_out, int out_size, void* d_ws, size_t ws_size,
                              hipStream_t stream) {
    const float* x        = (const float*)d_in[0];
    const float* prior    = (const float*)d_in[1];
    const float* w_qkv    = (const float*)d_in[2];
    const float* w_dw     = (const float*)d_in[3];
    const float* w_proj   = (const float*)d_in[4];
    const float* w_kernel = (const float*)d_in[5];
    const float* temp     = (const float*)d_in[6];
    char* ws = (char*)d_ws;
    float*  kv    = (float*)(ws + OFF_KV);
    float*  ssq   = (float*)(ws + OFF_SSQ);
    float*  S     = (float*)(ws + OFF_S);
    __bf16* Wb    = (__bf16*)(ws + OFF_WB);
    __bf16* M     = (__bf16*)(ws + OFF_M);
    __bf16* qkv2  = (__bf16*)(ws + OFF_QKV2);
    __bf16* qkv1  = (__bf16*)(ws + OFF_QKV1);
    float*  outp  = (float*)d_out;

    k_kv<<<12, 256, 0, stream>>>(prior, w_kernel, kv, (float*)(ws + OFF_SSQ));
    k_wcast<<<432, 256, 0, stream>>>(w_qkv, Wb);
    k_qkv<<<dim3(128, 8), 256, 0, stream>>>(x, kv, Wb, qkv1);
    k_dw<<<9216, 256, 0, stream>>>(qkv1, w_dw, qkv2, ssq);
    k_sdot<<<dim3(32, 4, 8), 256, 0, stream>>>(qkv2, S);
    k_soft<<<32, 256, 0, stream>>>(S, ssq, temp, w_proj, M);
    k_out<<<dim3(128, 8), 256, 0, stream>>>(M, qkv2, outp);
}

// Round 7
// 233.919 us; speedup vs baseline: 1.6552x; 1.0074x over previous
//
#include <hip/hip_runtime.h>
#include <hip/hip_bf16.h>
#include <stdint.h>

typedef float f32x4 __attribute__((ext_vector_type(4)));
typedef __bf16 bf16x8 __attribute__((ext_vector_type(8)));
typedef __bf16 bf16x2 __attribute__((ext_vector_type(2)));

#define NB 8
#define NC 192
#define NO 576
#define NH 128
#define NWID 128
#define NSP 16384
#define NHEADS 4
#define NCH 48

// workspace layout (bytes)
#define OFF_KV    0u
#define OFF_SSQ   12288u        // ssq 12288 B + S 294912 B contiguous (zeroed by k_kv)
#define OFF_S     24576u
#define OFF_WB    319488u       // 221184 B
#define OFF_M     540672u       // 589824 B
#define OFF_QKV2  1130496u      // 150994944 B
#define OFF_QKV1  152125440u    // 150994944 B

// async global->LDS DMA, 16B per lane; LDS dest is wave-uniform base + lane*16
__device__ __forceinline__ void g2l16(const void* g, void* l) {
    __builtin_amdgcn_global_load_lds((const __attribute__((address_space(1))) void*)g,
                                     (__attribute__((address_space(3))) void*)l, 16, 0, 0);
}

// ---------------- kernel 1: kv = prior @ w_kernel^T (8 x 384); also zeroes ssq+S ----------------
__global__ void k_kv(const float* __restrict__ prior, const float* __restrict__ w_kernel,
                     float* __restrict__ kv, float* __restrict__ zbase) {
    int t = blockIdx.x * 256 + threadIdx.x;
    for (int i = t; i < 76800; i += 3072) zbase[i] = 0.f;   // ssq(3072f) + S(73728f)
    if (t >= NB * 384) return;
    int b = t / 384, j = t % 384;
    const float* p = prior + b * NC;
    const float* wk = w_kernel + j * NC;
    float s = 0.f;
    for (int f = 0; f < NC; ++f) s += p[f] * wk[f];
    kv[t] = s;
}

// ---------------- kernel 2: cast w_qkv -> bf16 ----------------
__global__ void k_wcast(const float* __restrict__ w_qkv, __bf16* __restrict__ Wb) {
    int t = blockIdx.x * 256 + threadIdx.x;
    if (t < NO * NC) Wb[t] = (__bf16)w_qkv[t];
}

// ---------------- kernel 3: qkv GEMM, fused affine+transpose staging, 9 A-tiles looped ----------------
// Swizzle involution everywhere: chunk_slot = chunk ^ ((row>>2)&7).
// B tile 128n x 192c bf16 = 48KB at lds[0] (built in-kernel from fp32 x via f32x4 loads).
// A tile (Wb) 64x192 = 24KB at lds[49152] via DMA with pre-swizzled source.
__global__ __launch_bounds__(256, 2) void k_qkv(const float* __restrict__ x, const float* __restrict__ kv,
                                                const __bf16* __restrict__ Wb, __bf16* __restrict__ qkv1) {
    __shared__ __align__(16) char lds[73728];
    int b = blockIdx.y, n0 = blockIdx.x * 128;
    int t = threadIdx.x;
    // A-tile 0 DMA (vmcnt-tracked)
#pragma unroll
    for (int i = 0; i < 6; ++i) {
        int s = i * 256 + t;
        int r = s / 24, c = s % 24, g = c ^ ((r >> 2) & 7);
        g2l16(Wb + (size_t)r * NC + g * 8, lds + 49152 + s * 16);
    }
    // B-tile: f32x4 loads along n, affine, scalar swizzled bf16 LDS writes (k_xt pattern)
    const float* xb = x + (size_t)b * NC * NSP + n0;
    const float* kvb = kv + b * 384;
#pragma unroll 4
    for (int p = 0; p < 24; ++p) {
        int id = p * 256 + t;
        int c = id >> 5, n4 = (id & 31) << 2;
        f32x4 v = *reinterpret_cast<const f32x4*>(xb + (size_t)c * NSP + n4);
        float k1 = kvb[c], k2 = kvb[192 + c];
        int chi = (c >> 3) ^ ((n4 >> 2) & 7);   // (n4+j)>>2 == n4>>2 for j<4
        int base = chi * 16 + (c & 7) * 2;
#pragma unroll
        for (int j = 0; j < 4; ++j)
            *reinterpret_cast<__bf16*>((char*)lds + (n4 + j) * 384 + base) = (__bf16)(v[j] * k1 + k2);
    }
    asm volatile("s_waitcnt vmcnt(0)" ::: "memory");
    __syncthreads();
    int w = t >> 6, l = t & 63, lr = l & 15, lg = l >> 4;
    // hoist B fragments into registers (read LDS B once)
    bf16x8 bgf[6][2];
#pragma unroll
    for (int ks = 0; ks < 6; ++ks) {
        int c16 = ks * 4 + lg;
#pragma unroll
        for (int nf = 0; nf < 2; ++nf) {
            int r = w * 32 + nf * 16 + lr;
            bgf[ks][nf] = *reinterpret_cast<const bf16x8*>(lds + r * 384 + ((c16 ^ ((r >> 2) & 7)) << 4));
        }
    }
    for (int ot = 0; ot < 9; ++ot) {
        f32x4 acc[4][2] = {};
#pragma unroll
        for (int ks = 0; ks < 6; ++ks) {
            int c16 = ks * 4 + lg;
            bf16x8 a[4];
#pragma unroll
            for (int mf = 0; mf < 4; ++mf) {
                int r = mf * 16 + lr;
                a[mf] = *reinterpret_cast<const bf16x8*>(lds + 49152 + r * 384 + ((c16 ^ ((r >> 2) & 7)) << 4));
            }
#pragma unroll
            for (int mf = 0; mf < 4; ++mf)
#pragma unroll
                for (int nf = 0; nf < 2; ++nf)
                    acc[mf][nf] = __builtin_amdgcn_mfma_f32_16x16x32_bf16(a[mf], bgf[ks][nf], acc[mf][nf], 0, 0, 0);
        }
        __syncthreads();              // all waves done reading A(ot)
        if (ot < 8) {
            const __bf16* asrc = Wb + (size_t)(ot + 1) * 64 * NC;
#pragma unroll
            for (int i = 0; i < 6; ++i) {
                int s = i * 256 + t;
                int r = s / 24, c = s % 24, g = c ^ ((r >> 2) & 7);
                g2l16(asrc + (size_t)r * NC + g * 8, lds + 49152 + s * 16);
            }
        }
        int o0 = ot * 64;
#pragma unroll
        for (int mf = 0; mf < 4; ++mf)
#pragma unroll
            for (int rr = 0; rr < 4; ++rr) {
                int orow = o0 + mf * 16 + lg * 4 + rr;
#pragma unroll
                for (int nf = 0; nf < 2; ++nf)
                    qkv1[(size_t)(b * NO + orow) * NSP + n0 + w * 32 + nf * 16 + lr] = (__bf16)acc[mf][nf][rr];
            }
        if (ot < 8) {
            // 6 DMAs issued first, then 32 stores: vmcnt(32) => 6 oldest (DMAs) retired
            asm volatile("s_waitcnt vmcnt(32)" ::: "memory");
            __syncthreads();
        }
    }
}

// ---------------- kernel 4: depthwise 3x3 conv + sumsq(q,k), register-rolling ----------------
__global__ __launch_bounds__(256) void k_dw(const __bf16* __restrict__ qkv1, const float* __restrict__ w_dw,
                                            __bf16* __restrict__ qkv2, float* __restrict__ ssq) {
    int task = blockIdx.x * 4 + (threadIdx.x >> 6);
    int l = threadIdx.x & 63;
    int strip = task & 7;
    int bo = task >> 3;
    int o = bo % NO, b = bo / NO;
    const __bf16* src = qkv1 + (size_t)bo * NSP;
    __bf16* dst = qkv2 + (size_t)bo * NSP;
    float wd[9];
#pragma unroll
    for (int i = 0; i < 9; ++i) wd[i] = w_dw[o * 9 + i];
    int ys = strip * 16;
    float a0, b0, L0, R0, a1, b1, L1, R1, a2, b2, L2, R2;

#define LOADROW(Y, A, B, L_, R_) {                                            \
        bf16x2 p = {};                                                        \
        int y_ = (Y);                                                         \
        if (y_ >= 0 && y_ < NH) p = *reinterpret_cast<const bf16x2*>(src + y_ * NWID + 2 * l); \
        A = (float)p[0]; B = (float)p[1];                                     \
        L_ = __shfl(B, l - 1); R_ = __shfl(A, l + 1);                         \
        if (l == 0) L_ = 0.f;                                                 \
        if (l == 63) R_ = 0.f; }

    LOADROW(ys - 1, a0, b0, L0, R0)
    LOADROW(ys,     a1, b1, L1, R1)
    float ss = 0.f;
    bool qk = (o < 384);
#pragma unroll 4
    for (int i = 0; i < 16; ++i) {
        LOADROW(ys + i + 1, a2, b2, L2, R2)
        float oa = L0 * wd[0] + a0 * wd[1] + b0 * wd[2]
                 + L1 * wd[3] + a1 * wd[4] + b1 * wd[5]
                 + L2 * wd[6] + a2 * wd[7] + b2 * wd[8];
        float ob = a0 * wd[0] + b0 * wd[1] + R0 * wd[2]
                 + a1 * wd[3] + b1 * wd[4] + R1 * wd[5]
                 + a2 * wd[6] + b2 * wd[7] + R2 * wd[8];
        bf16x2 ov; ov[0] = (__bf16)oa; ov[1] = (__bf16)ob;
        *reinterpret_cast<bf16x2*>(dst + (ys + i) * NWID + 2 * l) = ov;
        if (qk) { float fa = (float)ov[0], fb = (float)ov[1]; ss += fa * fa + fb * fb; }
        a0 = a1; b0 = b1; L0 = L1; R0 = R1;
        a1 = a2; b1 = b2; L1 = L2; R1 = R2;
    }
#undef LOADROW
    if (qk) {
        for (int off = 32; off > 0; off >>= 1) ss += __shfl_down(ss, off);
        if (l == 0) atomicAdd(&ssq[b * 384 + o], ss);
    }
}

// ---------------- kernel 5: Gram dots, staged 2-pass; S += q.k^T over n-chunk 512 ----------------
__global__ __launch_bounds__(256, 3) void k_sdot(const __bf16* __restrict__ qkv2, float* __restrict__ S) {
    __shared__ __align__(16) char lds[49152];
    int b = blockIdx.z, h = blockIdx.y, n0 = blockIdx.x * 512;
    int t = threadIdx.x;
    int w = t >> 6, l = t & 63, lr = l & 15, lg = l >> 4;
    const __bf16* qsrc = qkv2 + (size_t)(b * NO + h * NCH) * NSP + n0;
    const __bf16* ksrc = qkv2 + (size_t)(b * NO + 192 + h * NCH) * NSP + n0;
    f32x4 acc[3][3] = {};
    for (int pass = 0; pass < 2; ++pass) {
        if (pass) __syncthreads();
        int coff = pass * 256;
#pragma unroll
        for (int i = 0; i < 6; ++i) {
            int s = i * 256 + t;
            int r = s >> 5, c = s & 31, g = c ^ (r & 7);
            g2l16(qsrc + (size_t)r * NSP + coff + g * 8, lds + s * 16);
        }
#pragma unroll
        for (int i = 0; i < 6; ++i) {
            int s = i * 256 + t;
            int r = s >> 5, c = s & 31, g = c ^ (r & 7);
            g2l16(ksrc + (size_t)r * NSP + coff + g * 8, lds + 24576 + s * 16);
        }
        asm volatile("s_waitcnt vmcnt(0)" ::: "memory");
        __syncthreads();
#pragma unroll
        for (int j = 0; j < 2; ++j) {
            int c16 = (w * 2 + j) * 4 + lg;
            bf16x8 a[3], bb[3];
#pragma unroll
            for (int mf = 0; mf < 3; ++mf) {
                int r = mf * 16 + lr;
                a[mf] = *reinterpret_cast<const bf16x8*>(lds + r * 512 + ((c16 ^ (r & 7)) << 4));
            }
#pragma unroll
            for (int nf = 0; nf < 3; ++nf) {
                int r = nf * 16 + lr;
                bb[nf] = *reinterpret_cast<const bf16x8*>(lds + 24576 + r * 512 + ((c16 ^ (r & 7)) << 4));
            }
#pragma unroll
            for (int mf = 0; mf < 3; ++mf)
#pragma unroll
                for (int nf = 0; nf < 3; ++nf)
                    acc[mf][nf] = __builtin_amdgcn_mfma_f32_16x16x32_bf16(a[mf], bb[nf], acc[mf][nf], 0, 0, 0);
        }
    }
    __syncthreads();
    float* red = (float*)lds;
#pragma unroll
    for (int mf = 0; mf < 3; ++mf)
#pragma unroll
        for (int nf = 0; nf < 3; ++nf)
#pragma unroll
            for (int r = 0; r < 4; ++r) {
                int c = mf * 16 + lg * 4 + r, d = nf * 16 + lr;
                red[(w * 48 + c) * 49 + d] = acc[mf][nf][r];
            }
    __syncthreads();
    float* Sb = S + (size_t)(b * NHEADS + h) * NCH * NCH;
    for (int i = 0; i < 9; ++i) {
        int idx = t + i * 256;
        int c = idx / 48, d = idx % 48;
        float s = red[c * 49 + d] + red[(48 + c) * 49 + d] + red[(96 + c) * 49 + d] + red[(144 + c) * 49 + d];
        atomicAdd(&Sb[c * 48 + d], s);
    }
}

// ---------------- kernel 6: normalize + softmax + fold proj ----------------
__global__ __launch_bounds__(256) void k_soft(const float* __restrict__ S, const float* __restrict__ ssq,
                                              const float* __restrict__ temp, const float* __restrict__ w_proj,
                                              __bf16* __restrict__ M) {
    int b = blockIdx.x / NHEADS, h = blockIdx.x % NHEADS;
    int tid = threadIdx.x;
    __shared__ float attn[48][48];
    __shared__ float inv[96];
    if (tid < 96) {
        int c = tid % 48;
        int isK = tid / 48;
        float v = ssq[b * 384 + isK * 192 + h * NCH + c];
        float nrm = fmaxf(sqrtf(v), 1e-12f);
        inv[tid] = 1.f / nrm;
    }
    __syncthreads();
    float tp = temp[h];
    const float* Sb = S + (size_t)(b * NHEADS + h) * NCH * NCH;
    for (int i = 0; i < 9; ++i) {
        int idx = tid + i * 256;
        int c = idx / 48, d = idx % 48;
        attn[c][d] = Sb[c * 48 + d] * inv[c] * inv[48 + d] * tp;
    }
    __syncthreads();
    if (tid < 48) {
        float m = -1e30f;
        for (int d = 0; d < 48; ++d) m = fmaxf(m, attn[tid][d]);
        float sum = 0.f;
        for (int d = 0; d < 48; ++d) { float e = __expf(attn[tid][d] - m); attn[tid][d] = e; sum += e; }
        float r = 1.f / sum;
        for (int d = 0; d < 48; ++d) attn[tid][d] *= r;
    }
    __syncthreads();
    for (int i = 0; i < 36; ++i) {
        int idx = tid + i * 256;
        int oo = idx / 48, d = idx % 48;
        const float* wp = w_proj + oo * NC + h * NCH;
        float s = 0.f;
        for (int c = 0; c < 48; ++c) s += wp[c] * attn[c][d];
        M[(size_t)(b * NC + oo) * NC + h * NCH + d] = (__bf16)s;
    }
}

// ---------------- kernel 7: final GEMM, fused v-transpose staging, 3 A-tiles looped ----------------
__global__ __launch_bounds__(256, 2) void k_out(const __bf16* __restrict__ Mw, const __bf16* __restrict__ qkv2,
                                                float* __restrict__ outp) {
    __shared__ __align__(16) char lds[73728];
    int b = blockIdx.y, n0 = blockIdx.x * 128;
    int t = threadIdx.x;
    // A-tile 0 DMA
    const __bf16* asrc0 = Mw + (size_t)(b * NC) * NC;
#pragma unroll
    for (int i = 0; i < 6; ++i) {
        int s = i * 256 + t;
        int r = s / 24, c = s % 24, g = c ^ ((r >> 2) & 7);
        g2l16(asrc0 + (size_t)r * NC + g * 8, lds + 49152 + s * 16);
    }
    // B-tile: bf16x8 loads along n, scalar swizzled LDS writes
    const __bf16* vb = qkv2 + (size_t)(b * NO + 384) * NSP + n0;
#pragma unroll 2
    for (int p = 0; p < 12; ++p) {
        int id = p * 256 + t;
        int c = id >> 4, n8 = (id & 15) << 3;
        bf16x8 vv = *reinterpret_cast<const bf16x8*>(vb + (size_t)c * NSP + n8);
        int cb = c >> 3, cl = (c & 7) * 2;
#pragma unroll
        for (int j = 0; j < 8; ++j) {
            int n = n8 + j;
            int chi = cb ^ ((n >> 2) & 7);
            *reinterpret_cast<__bf16*>((char*)lds + n * 384 + chi * 16 + cl) = vv[j];
        }
    }
    asm volatile("s_waitcnt vmcnt(0)" ::: "memory");
    __syncthreads();
    int w = t >> 6, l = t & 63, lr = l & 15, lg = l >> 4;
    bf16x8 bgf[6][2];
#pragma unroll
    for (int ks = 0; ks < 6; ++ks) {
        int c16 = ks * 4 + lg;
#pragma unroll
        for (int nf = 0; nf < 2; ++nf) {
            int r = w * 32 + nf * 16 + lr;
            bgf[ks][nf] = *reinterpret_cast<const bf16x8*>(lds + r * 384 + ((c16 ^ ((r >> 2) & 7)) << 4));
        }
    }
    for (int ot = 0; ot < 3; ++ot) {
        f32x4 acc[4][2] = {};
#pragma unroll
        for (int ks = 0; ks < 6; ++ks) {
            int c16 = ks * 4 + lg;
            bf16x8 a[4];
#pragma unroll
            for (int mf = 0; mf < 4; ++mf) {
                int r = mf * 16 + lr;
                a[mf] = *reinterpret_cast<const bf16x8*>(lds + 49152 + r * 384 + ((c16 ^ ((r >> 2) & 7)) << 4));
            }
#pragma unroll
            for (int mf = 0; mf < 4; ++mf)
#pragma unroll
                for (int nf = 0; nf < 2; ++nf)
                    acc[mf][nf] = __builtin_amdgcn_mfma_f32_16x16x32_bf16(a[mf], bgf[ks][nf], acc[mf][nf], 0, 0, 0);
        }
        __syncthreads();
        if (ot < 2) {
            const __bf16* asrc = Mw + (size_t)(b * NC + (ot + 1) * 64) * NC;
#pragma unroll
            for (int i = 0; i < 6; ++i) {
                int s = i * 256 + t;
                int r = s / 24, c = s % 24, g = c ^ ((r >> 2) & 7);
                g2l16(asrc + (size_t)r * NC + g * 8, lds + 49152 + s * 16);
            }
        }
        int o0 = ot * 64;
#pragma unroll
        for (int mf = 0; mf < 4; ++mf)
#pragma unroll
            for (int rr = 0; rr < 4; ++rr) {
                int orow = o0 + mf * 16 + lg * 4 + rr;
#pragma unroll
                for (int nf = 0; nf < 2; ++nf)
                    outp[(size_t)(b * NC + orow) * NSP + n0 + w * 32 + nf * 16 + lr] = acc[mf][nf][rr];
            }
        if (ot < 2) {
            asm volatile("s_waitcnt vmcnt(32)" ::: "memory");
            __syncthreads();
        }
    }
}

extern "C" void kernel_launch(void* const* d_in, const int* in_sizes, int n_in,
                              void* d_out, int out_size, void* d_ws, size_t ws_size,
                              hipStream_t stream) {
    const float* x        = (const float*)d_in[0];
    const float* prior    = (const float*)d_in[1];
    const float* w_qkv    = (const float*)d_in[2];
    const float* w_dw     = (const float*)d_in[3];
    const float* w_proj   = (const float*)d_in[4];
    const float* w_kernel = (const float*)d_in[5];
    const float* temp     = (const float*)d_in[6];
    char* ws = (char*)d_ws;
    float*  kv    = (float*)(ws + OFF_KV);
    float*  ssq   = (float*)(ws + OFF_SSQ);
    float*  S     = (float*)(ws + OFF_S);
    __bf16* Wb    = (__bf16*)(ws + OFF_WB);
    __bf16* M     = (__bf16*)(ws + OFF_M);
    __bf16* qkv2  = (__bf16*)(ws + OFF_QKV2);
    __bf16* qkv1  = (__bf16*)(ws + OFF_QKV1);
    float*  outp  = (float*)d_out;

    k_kv<<<12, 256, 0, stream>>>(prior, w_kernel, kv, (float*)(ws + OFF_SSQ));
    k_wcast<<<432, 256, 0, stream>>>(w_qkv, Wb);
    k_qkv<<<dim3(128, 8), 256, 0, stream>>>(x, kv, Wb, qkv1);
    k_dw<<<9216, 256, 0, stream>>>(qkv1, w_dw, qkv2, ssq);
    k_sdot<<<dim3(32, 4, 8), 256, 0, stream>>>(qkv2, S);
    k_soft<<<32, 256, 0, stream>>>(S, ssq, temp, w_proj, M);
    k_out<<<dim3(128, 8), 256, 0, stream>>>(M, qkv2, outp);
}

// Round 8
// 227.759 us; speedup vs baseline: 1.7000x; 1.0270x over previous
//
#include <hip/hip_runtime.h>
#include <hip/hip_bf16.h>
#include <stdint.h>

typedef float f32x4 __attribute__((ext_vector_type(4)));
typedef __bf16 bf16x8 __attribute__((ext_vector_type(8)));
typedef __bf16 bf16x4 __attribute__((ext_vector_type(4)));
typedef __bf16 bf16x2 __attribute__((ext_vector_type(2)));

#define NB 8
#define NC 192
#define NO 576
#define NH 128
#define NWID 128
#define NSP 16384
#define NHEADS 4
#define NCH 48

// workspace layout (bytes)
#define OFF_KV    0u
#define OFF_SSQ   12288u        // ssq 12288 B + S 294912 B contiguous (zeroed by k_kv)
#define OFF_S     24576u
#define OFF_WB    319488u       // 221184 B
#define OFF_M     540672u       // 589824 B
#define OFF_QKV2  1130496u      // 150994944 B
#define OFF_QKV1  152125440u    // 150994944 B

// swizzle involution: chunk_slot = chunk ^ GR(row). Conflict-free for b128 reads over
// 16 consecutive rows (8 distinct banksets, 2-way=free) AND spread for stride-4-row writes.
#define GR(r) (((r) ^ ((r) >> 2)) & 7)

// async global->LDS DMA, 16B per lane; LDS dest is wave-uniform base + lane*16
__device__ __forceinline__ void g2l16(const void* g, void* l) {
    __builtin_amdgcn_global_load_lds((const __attribute__((address_space(1))) void*)g,
                                     (__attribute__((address_space(3))) void*)l, 16, 0, 0);
}

// ---------------- kernel 1: kv = prior @ w_kernel^T (8 x 384); also zeroes ssq+S ----------------
__global__ void k_kv(const float* __restrict__ prior, const float* __restrict__ w_kernel,
                     float* __restrict__ kv, float* __restrict__ zbase) {
    int t = blockIdx.x * 256 + threadIdx.x;
    for (int i = t; i < 76800; i += 3072) zbase[i] = 0.f;   // ssq(3072f) + S(73728f)
    if (t >= NB * 384) return;
    int b = t / 384, j = t % 384;
    const float* p = prior + b * NC;
    const float* wk = w_kernel + j * NC;
    float s = 0.f;
    for (int f = 0; f < NC; ++f) s += p[f] * wk[f];
    kv[t] = s;
}

// ---------------- kernel 2: cast w_qkv -> bf16 ----------------
__global__ void k_wcast(const float* __restrict__ w_qkv, __bf16* __restrict__ Wb) {
    int t = blockIdx.x * 256 + threadIdx.x;
    if (t < NO * NC) Wb[t] = (__bf16)w_qkv[t];
}

// ---------------- kernel 3: qkv GEMM, A double-buffered 32-row tiles (18 phases) ----------------
// B tile 128n x 192c bf16 = 48KB at lds[0] (built in-kernel from fp32 x).
// A buffers: 2 x 32rows x 192 = 2 x 12KB at lds[49152], DMA'd with pre-swizzled source.
__global__ __launch_bounds__(256, 2) void k_qkv(const float* __restrict__ x, const float* __restrict__ kv,
                                                const __bf16* __restrict__ Wb, __bf16* __restrict__ qkv1) {
    __shared__ __align__(16) char lds[73728];
    int b = blockIdx.y, n0 = blockIdx.x * 128;
    int t = threadIdx.x;
    // A-tile 0 DMA into buf0 (32 rows x 24 chunks = 768 slots, 3/thread)
#pragma unroll
    for (int i = 0; i < 3; ++i) {
        int s = i * 256 + t;
        int r = s / 24, c = s % 24, g = c ^ GR(r);
        g2l16(Wb + (size_t)r * NC + g * 8, lds + 49152 + s * 16);
    }
    // B-tile: f32x4 loads along n, affine, scalar swizzled bf16 LDS writes
    const float* xb = x + (size_t)b * NC * NSP + n0;
    const float* kvb = kv + b * 384;
#pragma unroll 4
    for (int p = 0; p < 24; ++p) {
        int id = p * 256 + t;
        int c = id >> 5, n4 = (id & 31) << 2;
        f32x4 v = *reinterpret_cast<const f32x4*>(xb + (size_t)c * NSP + n4);
        float k1 = kvb[c], k2 = kvb[192 + c];
#pragma unroll
        for (int j = 0; j < 4; ++j) {
            int n = n4 + j;
            int chi = (c >> 3) ^ GR(n);
            *reinterpret_cast<__bf16*>((char*)lds + n * 384 + chi * 16 + (c & 7) * 2) = (__bf16)(v[j] * k1 + k2);
        }
    }
    asm volatile("s_waitcnt vmcnt(0)" ::: "memory");
    __syncthreads();
    int w = t >> 6, l = t & 63, lr = l & 15, lg = l >> 4;
    // hoist B fragments into registers (read LDS B once)
    bf16x8 bgf[6][2];
#pragma unroll
    for (int ks = 0; ks < 6; ++ks) {
        int c16 = ks * 4 + lg;
#pragma unroll
        for (int nf = 0; nf < 2; ++nf) {
            int r = w * 32 + nf * 16 + lr;
            bgf[ks][nf] = *reinterpret_cast<const bf16x8*>(lds + r * 384 + ((c16 ^ GR(r)) << 4));
        }
    }
    // 18 phases over 32-row A tiles; prefetch depth 1
    for (int p = 0; p < 18; ++p) {
        int cur = p & 1;
        if (p < 17) {   // issue next-tile DMAs FIRST so latency hides under MFMA+stores
            const __bf16* asrc = Wb + (size_t)(p + 1) * 32 * NC;
#pragma unroll
            for (int i = 0; i < 3; ++i) {
                int s = i * 256 + t;
                int r = s / 24, c = s % 24, g = c ^ GR(r);
                g2l16(asrc + (size_t)r * NC + g * 8, lds + 49152 + (cur ^ 1) * 12288 + s * 16);
            }
        }
        f32x4 acc[2][2] = {};
#pragma unroll
        for (int ks = 0; ks < 6; ++ks) {
            int c16 = ks * 4 + lg;
            bf16x8 a[2];
#pragma unroll
            for (int mf = 0; mf < 2; ++mf) {
                int r = mf * 16 + lr;
                a[mf] = *reinterpret_cast<const bf16x8*>(lds + 49152 + cur * 12288 + r * 384 + ((c16 ^ GR(r)) << 4));
            }
#pragma unroll
            for (int mf = 0; mf < 2; ++mf)
#pragma unroll
                for (int nf = 0; nf < 2; ++nf)
                    acc[mf][nf] = __builtin_amdgcn_mfma_f32_16x16x32_bf16(a[mf], bgf[ks][nf], acc[mf][nf], 0, 0, 0);
        }
        int o0 = p * 32;
#pragma unroll
        for (int mf = 0; mf < 2; ++mf)
#pragma unroll
            for (int rr = 0; rr < 4; ++rr) {
                int orow = o0 + mf * 16 + lg * 4 + rr;
#pragma unroll
                for (int nf = 0; nf < 2; ++nf)
                    qkv1[(size_t)(b * NO + orow) * NSP + n0 + w * 32 + nf * 16 + lr] = (__bf16)acc[mf][nf][rr];
            }
        if (p < 17) {
            // outstanding: <=16 prev stores + 3 DMA + 16 stores; in-order retire =>
            // waiting to 16 drains prev stores AND this phase's 3 DMAs.
            asm volatile("s_waitcnt vmcnt(16)" ::: "memory");
            __syncthreads();
        }
    }
}

// ---------------- kernel 4: depthwise 3x3 conv + sumsq(q,k), register-rolling ----------------
__global__ __launch_bounds__(256) void k_dw(const __bf16* __restrict__ qkv1, const float* __restrict__ w_dw,
                                            __bf16* __restrict__ qkv2, float* __restrict__ ssq) {
    int task = blockIdx.x * 4 + (threadIdx.x >> 6);
    int l = threadIdx.x & 63;
    int strip = task & 7;
    int bo = task >> 3;
    int o = bo % NO, b = bo / NO;
    const __bf16* src = qkv1 + (size_t)bo * NSP;
    __bf16* dst = qkv2 + (size_t)bo * NSP;
    float wd[9];
#pragma unroll
    for (int i = 0; i < 9; ++i) wd[i] = w_dw[o * 9 + i];
    int ys = strip * 16;
    float a0, b0, L0, R0, a1, b1, L1, R1, a2, b2, L2, R2;

#define LOADROW(Y, A, B, L_, R_) {                                            \
        bf16x2 p = {};                                                        \
        int y_ = (Y);                                                         \
        if (y_ >= 0 && y_ < NH) p = *reinterpret_cast<const bf16x2*>(src + y_ * NWID + 2 * l); \
        A = (float)p[0]; B = (float)p[1];                                     \
        L_ = __shfl(B, l - 1); R_ = __shfl(A, l + 1);                         \
        if (l == 0) L_ = 0.f;                                                 \
        if (l == 63) R_ = 0.f; }

    LOADROW(ys - 1, a0, b0, L0, R0)
    LOADROW(ys,     a1, b1, L1, R1)
    float ss = 0.f;
    bool qk = (o < 384);
#pragma unroll 4
    for (int i = 0; i < 16; ++i) {
        LOADROW(ys + i + 1, a2, b2, L2, R2)
        float oa = L0 * wd[0] + a0 * wd[1] + b0 * wd[2]
                 + L1 * wd[3] + a1 * wd[4] + b1 * wd[5]
                 + L2 * wd[6] + a2 * wd[7] + b2 * wd[8];
        float ob = a0 * wd[0] + b0 * wd[1] + R0 * wd[2]
                 + a1 * wd[3] + b1 * wd[4] + R1 * wd[5]
                 + a2 * wd[6] + b2 * wd[7] + R2 * wd[8];
        bf16x2 ov; ov[0] = (__bf16)oa; ov[1] = (__bf16)ob;
        *reinterpret_cast<bf16x2*>(dst + (ys + i) * NWID + 2 * l) = ov;
        if (qk) { float fa = (float)ov[0], fb = (float)ov[1]; ss += fa * fa + fb * fb; }
        a0 = a1; b0 = b1; L0 = L1; R0 = R1;
        a1 = a2; b1 = b2; L1 = L2; R1 = R2;
    }
#undef LOADROW
    if (qk) {
        for (int off = 32; off > 0; off >>= 1) ss += __shfl_down(ss, off);
        if (l == 0) atomicAdd(&ssq[b * 384 + o], ss);
    }
}

// ---------------- kernel 5: Gram dots, staged 2-pass; S += q.k^T over n-chunk 512 ----------------
__global__ __launch_bounds__(256, 3) void k_sdot(const __bf16* __restrict__ qkv2, float* __restrict__ S) {
    __shared__ __align__(16) char lds[49152];
    int b = blockIdx.z, h = blockIdx.y, n0 = blockIdx.x * 512;
    int t = threadIdx.x;
    int w = t >> 6, l = t & 63, lr = l & 15, lg = l >> 4;
    const __bf16* qsrc = qkv2 + (size_t)(b * NO + h * NCH) * NSP + n0;
    const __bf16* ksrc = qkv2 + (size_t)(b * NO + 192 + h * NCH) * NSP + n0;
    f32x4 acc[3][3] = {};
    for (int pass = 0; pass < 2; ++pass) {
        if (pass) __syncthreads();
        int coff = pass * 256;
#pragma unroll
        for (int i = 0; i < 6; ++i) {
            int s = i * 256 + t;
            int r = s >> 5, c = s & 31, g = c ^ (r & 7);
            g2l16(qsrc + (size_t)r * NSP + coff + g * 8, lds + s * 16);
        }
#pragma unroll
        for (int i = 0; i < 6; ++i) {
            int s = i * 256 + t;
            int r = s >> 5, c = s & 31, g = c ^ (r & 7);
            g2l16(ksrc + (size_t)r * NSP + coff + g * 8, lds + 24576 + s * 16);
        }
        asm volatile("s_waitcnt vmcnt(0)" ::: "memory");
        __syncthreads();
#pragma unroll
        for (int j = 0; j < 2; ++j) {
            int c16 = (w * 2 + j) * 4 + lg;
            bf16x8 a[3], bb[3];
#pragma unroll
            for (int mf = 0; mf < 3; ++mf) {
                int r = mf * 16 + lr;
                a[mf] = *reinterpret_cast<const bf16x8*>(lds + r * 512 + ((c16 ^ (r & 7)) << 4));
            }
#pragma unroll
            for (int nf = 0; nf < 3; ++nf) {
                int r = nf * 16 + lr;
                bb[nf] = *reinterpret_cast<const bf16x8*>(lds + 24576 + r * 512 + ((c16 ^ (r & 7)) << 4));
            }
#pragma unroll
            for (int mf = 0; mf < 3; ++mf)
#pragma unroll
                for (int nf = 0; nf < 3; ++nf)
                    acc[mf][nf] = __builtin_amdgcn_mfma_f32_16x16x32_bf16(a[mf], bb[nf], acc[mf][nf], 0, 0, 0);
        }
    }
    __syncthreads();
    float* red = (float*)lds;
#pragma unroll
    for (int mf = 0; mf < 3; ++mf)
#pragma unroll
        for (int nf = 0; nf < 3; ++nf)
#pragma unroll
            for (int r = 0; r < 4; ++r) {
                int c = mf * 16 + lg * 4 + r, d = nf * 16 + lr;
                red[(w * 48 + c) * 49 + d] = acc[mf][nf][r];
            }
    __syncthreads();
    float* Sb = S + (size_t)(b * NHEADS + h) * NCH * NCH;
    for (int i = 0; i < 9; ++i) {
        int idx = t + i * 256;
        int c = idx / 48, d = idx % 48;
        float s = red[c * 49 + d] + red[(48 + c) * 49 + d] + red[(96 + c) * 49 + d] + red[(144 + c) * 49 + d];
        atomicAdd(&Sb[c * 48 + d], s);
    }
}

// ---------------- kernel 6: normalize + softmax + fold proj ----------------
__global__ __launch_bounds__(256) void k_soft(const float* __restrict__ S, const float* __restrict__ ssq,
                                              const float* __restrict__ temp, const float* __restrict__ w_proj,
                                              __bf16* __restrict__ M) {
    int b = blockIdx.x / NHEADS, h = blockIdx.x % NHEADS;
    int tid = threadIdx.x;
    __shared__ float attn[48][48];
    __shared__ float inv[96];
    if (tid < 96) {
        int c = tid % 48;
        int isK = tid / 48;
        float v = ssq[b * 384 + isK * 192 + h * NCH + c];
        float nrm = fmaxf(sqrtf(v), 1e-12f);
        inv[tid] = 1.f / nrm;
    }
    __syncthreads();
    float tp = temp[h];
    const float* Sb = S + (size_t)(b * NHEADS + h) * NCH * NCH;
    for (int i = 0; i < 9; ++i) {
        int idx = tid + i * 256;
        int c = idx / 48, d = idx % 48;
        attn[c][d] = Sb[c * 48 + d] * inv[c] * inv[48 + d] * tp;
    }
    __syncthreads();
    if (tid < 48) {
        float m = -1e30f;
        for (int d = 0; d < 48; ++d) m = fmaxf(m, attn[tid][d]);
        float sum = 0.f;
        for (int d = 0; d < 48; ++d) { float e = __expf(attn[tid][d] - m); attn[tid][d] = e; sum += e; }
        float r = 1.f / sum;
        for (int d = 0; d < 48; ++d) attn[tid][d] *= r;
    }
    __syncthreads();
    for (int i = 0; i < 36; ++i) {
        int idx = tid + i * 256;
        int oo = idx / 48, d = idx % 48;
        const float* wp = w_proj + oo * NC + h * NCH;
        float s = 0.f;
        for (int c = 0; c < 48; ++c) s += wp[c] * attn[c][d];
        M[(size_t)(b * NC + oo) * NC + h * NCH + d] = (__bf16)s;
    }
}

// ---------------- kernel 7: final GEMM, fused v-transpose staging, 3 A-tiles looped ----------------
__global__ __launch_bounds__(256, 2) void k_out(const __bf16* __restrict__ Mw, const __bf16* __restrict__ qkv2,
                                                float* __restrict__ outp) {
    __shared__ __align__(16) char lds[73728];
    int b = blockIdx.y, n0 = blockIdx.x * 128;
    int t = threadIdx.x;
    // A-tile 0 DMA (64 rows x 24 chunks)
    const __bf16* asrc0 = Mw + (size_t)(b * NC) * NC;
#pragma unroll
    for (int i = 0; i < 6; ++i) {
        int s = i * 256 + t;
        int r = s / 24, c = s % 24, g = c ^ GR(r);
        g2l16(asrc0 + (size_t)r * NC + g * 8, lds + 49152 + s * 16);
    }
    // B-tile: bf16x4 loads along n, scalar swizzled LDS writes
    const __bf16* vb = qkv2 + (size_t)(b * NO + 384) * NSP + n0;
#pragma unroll 4
    for (int p = 0; p < 24; ++p) {
        int id = p * 256 + t;
        int c = id >> 5, n4 = (id & 31) << 2;
        bf16x4 vv = *reinterpret_cast<const bf16x4*>(vb + (size_t)c * NSP + n4);
#pragma unroll
        for (int j = 0; j < 4; ++j) {
            int n = n4 + j;
            int chi = (c >> 3) ^ GR(n);
            *reinterpret_cast<__bf16*>((char*)lds + n * 384 + chi * 16 + (c & 7) * 2) = vv[j];
        }
    }
    asm volatile("s_waitcnt vmcnt(0)" ::: "memory");
    __syncthreads();
    int w = t >> 6, l = t & 63, lr = l & 15, lg = l >> 4;
    bf16x8 bgf[6][2];
#pragma unroll
    for (int ks = 0; ks < 6; ++ks) {
        int c16 = ks * 4 + lg;
#pragma unroll
        for (int nf = 0; nf < 2; ++nf) {
            int r = w * 32 + nf * 16 + lr;
            bgf[ks][nf] = *reinterpret_cast<const bf16x8*>(lds + r * 384 + ((c16 ^ GR(r)) << 4));
        }
    }
    for (int ot = 0; ot < 3; ++ot) {
        f32x4 acc[4][2] = {};
#pragma unroll
        for (int ks = 0; ks < 6; ++ks) {
            int c16 = ks * 4 + lg;
            bf16x8 a[4];
#pragma unroll
            for (int mf = 0; mf < 4; ++mf) {
                int r = mf * 16 + lr;
                a[mf] = *reinterpret_cast<const bf16x8*>(lds + 49152 + r * 384 + ((c16 ^ GR(r)) << 4));
            }
#pragma unroll
            for (int mf = 0; mf < 4; ++mf)
#pragma unroll
                for (int nf = 0; nf < 2; ++nf)
                    acc[mf][nf] = __builtin_amdgcn_mfma_f32_16x16x32_bf16(a[mf], bgf[ks][nf], acc[mf][nf], 0, 0, 0);
        }
        __syncthreads();
        if (ot < 2) {
            const __bf16* asrc = Mw + (size_t)(b * NC + (ot + 1) * 64) * NC;
#pragma unroll
            for (int i = 0; i < 6; ++i) {
                int s = i * 256 + t;
                int r = s / 24, c = s % 24, g = c ^ GR(r);
                g2l16(asrc + (size_t)r * NC + g * 8, lds + 49152 + s * 16);
            }
        }
        int o0 = ot * 64;
#pragma unroll
        for (int mf = 0; mf < 4; ++mf)
#pragma unroll
            for (int rr = 0; rr < 4; ++rr) {
                int orow = o0 + mf * 16 + lg * 4 + rr;
#pragma unroll
                for (int nf = 0; nf < 2; ++nf)
                    outp[(size_t)(b * NC + orow) * NSP + n0 + w * 32 + nf * 16 + lr] = acc[mf][nf][rr];
            }
        if (ot < 2) {
            asm volatile("s_waitcnt vmcnt(32)" ::: "memory");
            __syncthreads();
        }
    }
}

extern "C" void kernel_launch(void* const* d_in, const int* in_sizes, int n_in,
                              void* d_out, int out_size, void* d_ws, size_t ws_size,
                              hipStream_t stream) {
    const float* x        = (const float*)d_in[0];
    const float* prior    = (const float*)d_in[1];
    const float* w_qkv    = (const float*)d_in[2];
    const float* w_dw     = (const float*)d_in[3];
    const float* w_proj   = (const float*)d_in[4];
    const float* w_kernel = (const float*)d_in[5];
    const float* temp     = (const float*)d_in[6];
    char* ws = (char*)d_ws;
    float*  kv    = (float*)(ws + OFF_KV);
    float*  ssq   = (float*)(ws + OFF_SSQ);
    float*  S     = (float*)(ws + OFF_S);
    __bf16* Wb    = (__bf16*)(ws + OFF_WB);
    __bf16* M     = (__bf16*)(ws + OFF_M);
    __bf16* qkv2  = (__bf16*)(ws + OFF_QKV2);
    __bf16* qkv1  = (__bf16*)(ws + OFF_QKV1);
    float*  outp  = (float*)d_out;

    k_kv<<<12, 256, 0, stream>>>(prior, w_kernel, kv, (float*)(ws + OFF_SSQ));
    k_wcast<<<432, 256, 0, stream>>>(w_qkv, Wb);
    k_qkv<<<dim3(128, 8), 256, 0, stream>>>(x, kv, Wb, qkv1);
    k_dw<<<9216, 256, 0, stream>>>(qkv1, w_dw, qkv2, ssq);
    k_sdot<<<dim3(32, 4, 8), 256, 0, stream>>>(qkv2, S);
    k_soft<<<32, 256, 0, stream>>>(S, ssq, temp, w_proj, M);
    k_out<<<dim3(128, 8), 256, 0, stream>>>(M, qkv2, outp);
}

// Round 9
// 225.357 us; speedup vs baseline: 1.7181x; 1.0107x over previous
//
#include <hip/hip_runtime.h>
#include <hip/hip_bf16.h>
#include <stdint.h>

typedef float f32x4 __attribute__((ext_vector_type(4)));
typedef __bf16 bf16x8 __attribute__((ext_vector_type(8)));
typedef __bf16 bf16x4 __attribute__((ext_vector_type(4)));
typedef __bf16 bf16x2 __attribute__((ext_vector_type(2)));

#define NB 8
#define NC 192
#define NO 576
#define NH 128
#define NWID 128
#define NSP 16384
#define NHEADS 4
#define NCH 48

// workspace layout (bytes) -- r5-proven
#define OFF_KV    0u
#define OFF_SSQ   12288u        // ssq 3072 f32 + S 73728 f32 contiguous (zeroed by k_prep)
#define OFF_S     24576u
#define OFF_WB    319488u       // 221184 B
#define OFF_M     540672u       // 589824 B
#define OFF_XT    1130496u      // xt 50331648 B; qkv2 aliases (xt dead after k_qkv): 150994944 B
#define OFF_QKV1  152125440u    // 150994944 B

#define GR(r) (((r) ^ ((r) >> 2)) & 7)

// async global->LDS DMA, 16B per lane; LDS dest is wave-uniform base + lane*16
__device__ __forceinline__ void g2l16(const void* g, void* l) {
    __builtin_amdgcn_global_load_lds((const __attribute__((address_space(1))) void*)g,
                                     (__attribute__((address_space(3))) void*)l, 16, 0, 0);
}

// ---------------- kernel 1: prep = zero(ssq,S) + Wb cast + kv GEMM ----------------
__global__ void k_prep(const float* __restrict__ prior, const float* __restrict__ w_kernel,
                       const float* __restrict__ w_qkv, float* __restrict__ kv,
                       float* __restrict__ zbase, __bf16* __restrict__ Wb) {
    int t = blockIdx.x * 256 + threadIdx.x;
    if (t < 76800) zbase[t] = 0.f;
    if (t < NO * NC) Wb[t] = (__bf16)w_qkv[t];
    if (t < NB * 384) {
        int b = t / 384, j = t % 384;
        const float* p = prior + b * NC;
        const float* wk = w_kernel + j * NC;
        float s = 0.f;
        for (int f = 0; f < NC; ++f) s += p[f] * wk[f];
        kv[t] = s;
    }
}

// ---------------- kernel 2: x~ = x*kv1 + kv2, transposed to [b][n][c] bf16 (r5-proven) ----------------
__global__ __launch_bounds__(256) void k_xt(const float* __restrict__ x, const float* __restrict__ kv,
                                            __bf16* __restrict__ xt) {
    int b = blockIdx.y;
    int n0 = blockIdx.x * 128;
    __shared__ __align__(16) __bf16 lds[128 * 192];
    int t = threadIdx.x;
    for (int p = 0; p < 24; ++p) {
        int id = p * 256 + t;
        int c = id >> 5, n4 = (id & 31) << 2;
        f32x4 v = *reinterpret_cast<const f32x4*>(x + (size_t)(b * NC + c) * NSP + n0 + n4);
        float k1 = kv[b * 384 + c], k2 = kv[b * 384 + 192 + c];
        int chi = (c >> 3) ^ ((n4 >> 2) & 7);
        int base = chi * 16 + (c & 7) * 2;
#pragma unroll
        for (int j = 0; j < 4; ++j)
            *reinterpret_cast<__bf16*>((char*)lds + (n4 + j) * 384 + base) = (__bf16)(v[j] * k1 + k2);
    }
    __syncthreads();
    for (int p = 0; p < 12; ++p) {
        int id = p * 256 + t;
        int n = id / 24, k = id % 24;
        bf16x8 r = *reinterpret_cast<const bf16x8*>((char*)lds + n * 384 + ((k ^ ((n >> 2) & 7)) << 4));
        *reinterpret_cast<bf16x8*>(xt + (size_t)(b * NSP + n0 + n) * NC + k * 8) = r;
    }
}

// ---------------- kernel 3: qkv GEMM (r5-proven): B staged once via DMA, 9 A-tiles looped ----------------
// B tile (xt) 128x192 bf16 = 48KB at lds[0]; A tile (Wb) 64x192 = 24KB at lds[49152].
// LDS slot (r, c) holds global chunk (c ^ (r&7)); read side applies same XOR.
__global__ __launch_bounds__(256, 2) void k_qkv(const __bf16* __restrict__ xt, const __bf16* __restrict__ Wb,
                                                __bf16* __restrict__ qkv1) {
    __shared__ __align__(16) char lds[73728];
    int b = blockIdx.y, n0 = blockIdx.x * 128;
    int t = threadIdx.x;
    const __bf16* bsrc = xt + (size_t)(b * NSP + n0) * NC;
#pragma unroll
    for (int i = 0; i < 12; ++i) {
        int s = i * 256 + t;
        int r = s / 24, c = s % 24, g = c ^ (r & 7);
        g2l16(bsrc + (size_t)r * NC + g * 8, lds + s * 16);
    }
#pragma unroll
    for (int i = 0; i < 6; ++i) {
        int s = i * 256 + t;
        int r = s / 24, c = s % 24, g = c ^ (r & 7);
        g2l16(Wb + (size_t)r * NC + g * 8, lds + 49152 + s * 16);
    }
    asm volatile("s_waitcnt vmcnt(0)" ::: "memory");
    __syncthreads();
    int w = t >> 6, l = t & 63, lr = l & 15, lg = l >> 4;
    // hoist B fragments into registers (read LDS B once)
    bf16x8 bgf[6][2];
#pragma unroll
    for (int ks = 0; ks < 6; ++ks) {
        int c16 = ks * 4 + lg;
#pragma unroll
        for (int nf = 0; nf < 2; ++nf) {
            int r = w * 32 + nf * 16 + lr;
            bgf[ks][nf] = *reinterpret_cast<const bf16x8*>(lds + r * 384 + ((c16 ^ (r & 7)) << 4));
        }
    }
    for (int ot = 0; ot < 9; ++ot) {
        f32x4 acc[4][2] = {};
#pragma unroll
        for (int ks = 0; ks < 6; ++ks) {
            int c16 = ks * 4 + lg;
            bf16x8 a[4];
#pragma unroll
            for (int mf = 0; mf < 4; ++mf) {
                int r = mf * 16 + lr;
                a[mf] = *reinterpret_cast<const bf16x8*>(lds + 49152 + r * 384 + ((c16 ^ (r & 7)) << 4));
            }
#pragma unroll
            for (int mf = 0; mf < 4; ++mf)
#pragma unroll
                for (int nf = 0; nf < 2; ++nf)
                    acc[mf][nf] = __builtin_amdgcn_mfma_f32_16x16x32_bf16(a[mf], bgf[ks][nf], acc[mf][nf], 0, 0, 0);
        }
        __syncthreads();              // all waves done reading A(ot)
        if (ot < 8) {
            const __bf16* asrc = Wb + (size_t)(ot + 1) * 64 * NC;
#pragma unroll
            for (int i = 0; i < 6; ++i) {
                int s = i * 256 + t;
                int r = s / 24, c = s % 24, g = c ^ (r & 7);
                g2l16(asrc + (size_t)r * NC + g * 8, lds + 49152 + s * 16);
            }
        }
        int o0 = ot * 64;
#pragma unroll
        for (int mf = 0; mf < 4; ++mf)
#pragma unroll
            for (int rr = 0; rr < 4; ++rr) {
                int orow = o0 + mf * 16 + lg * 4 + rr;
#pragma unroll
                for (int nf = 0; nf < 2; ++nf)
                    qkv1[(size_t)(b * NO + orow) * NSP + n0 + w * 32 + nf * 16 + lr] = (__bf16)acc[mf][nf][rr];
            }
        if (ot < 8) {
            // 6 DMAs issued first, then 32 stores: vmcnt(32) => 6 oldest (DMAs) retired
            asm volatile("s_waitcnt vmcnt(32)" ::: "memory");
            __syncthreads();
        }
    }
}

// ---------------- kernel 4: depthwise 3x3 conv + sumsq(q,k), register-rolling ----------------
__global__ __launch_bounds__(256) void k_dw(const __bf16* __restrict__ qkv1, const float* __restrict__ w_dw,
                                            __bf16* __restrict__ qkv2, float* __restrict__ ssq) {
    int task = blockIdx.x * 4 + (threadIdx.x >> 6);
    int l = threadIdx.x & 63;
    int strip = task & 7;
    int bo = task >> 3;
    int o = bo % NO, b = bo / NO;
    const __bf16* src = qkv1 + (size_t)bo * NSP;
    __bf16* dst = qkv2 + (size_t)bo * NSP;
    float wd[9];
#pragma unroll
    for (int i = 0; i < 9; ++i) wd[i] = w_dw[o * 9 + i];
    int ys = strip * 16;
    float a0, b0, L0, R0, a1, b1, L1, R1, a2, b2, L2, R2;

#define LOADROW(Y, A, B, L_, R_) {                                            \
        bf16x2 p = {};                                                        \
        int y_ = (Y);                                                         \
        if (y_ >= 0 && y_ < NH) p = *reinterpret_cast<const bf16x2*>(src + y_ * NWID + 2 * l); \
        A = (float)p[0]; B = (float)p[1];                                     \
        L_ = __shfl(B, l - 1); R_ = __shfl(A, l + 1);                         \
        if (l == 0) L_ = 0.f;                                                 \
        if (l == 63) R_ = 0.f; }

    LOADROW(ys - 1, a0, b0, L0, R0)
    LOADROW(ys,     a1, b1, L1, R1)
    float ss = 0.f;
    bool qk = (o < 384);
#pragma unroll 4
    for (int i = 0; i < 16; ++i) {
        LOADROW(ys + i + 1, a2, b2, L2, R2)
        float oa = L0 * wd[0] + a0 * wd[1] + b0 * wd[2]
                 + L1 * wd[3] + a1 * wd[4] + b1 * wd[5]
                 + L2 * wd[6] + a2 * wd[7] + b2 * wd[8];
        float ob = a0 * wd[0] + b0 * wd[1] + R0 * wd[2]
                 + a1 * wd[3] + b1 * wd[4] + R1 * wd[5]
                 + a2 * wd[6] + b2 * wd[7] + R2 * wd[8];
        bf16x2 ov; ov[0] = (__bf16)oa; ov[1] = (__bf16)ob;
        *reinterpret_cast<bf16x2*>(dst + (ys + i) * NWID + 2 * l) = ov;
        if (qk) { float fa = (float)ov[0], fb = (float)ov[1]; ss += fa * fa + fb * fb; }
        a0 = a1; b0 = b1; L0 = L1; R0 = R1;
        a1 = a2; b1 = b2; L1 = L2; R1 = R2;
    }
#undef LOADROW
    if (qk) {
        for (int off = 32; off > 0; off >>= 1) ss += __shfl_down(ss, off);
        if (l == 0) atomicAdd(&ssq[b * 384 + o], ss);
    }
}

// ---------------- kernel 5: Gram dots, staged 2-pass; S += q.k^T over n-chunk 512 ----------------
__global__ __launch_bounds__(256, 3) void k_sdot(const __bf16* __restrict__ qkv2, float* __restrict__ S) {
    __shared__ __align__(16) char lds[49152];
    int b = blockIdx.z, h = blockIdx.y, n0 = blockIdx.x * 512;
    int t = threadIdx.x;
    int w = t >> 6, l = t & 63, lr = l & 15, lg = l >> 4;
    const __bf16* qsrc = qkv2 + (size_t)(b * NO + h * NCH) * NSP + n0;
    const __bf16* ksrc = qkv2 + (size_t)(b * NO + 192 + h * NCH) * NSP + n0;
    f32x4 acc[3][3] = {};
    for (int pass = 0; pass < 2; ++pass) {
        if (pass) __syncthreads();
        int coff = pass * 256;
#pragma unroll
        for (int i = 0; i < 6; ++i) {
            int s = i * 256 + t;
            int r = s >> 5, c = s & 31, g = c ^ (r & 7);
            g2l16(qsrc + (size_t)r * NSP + coff + g * 8, lds + s * 16);
        }
#pragma unroll
        for (int i = 0; i < 6; ++i) {
            int s = i * 256 + t;
            int r = s >> 5, c = s & 31, g = c ^ (r & 7);
            g2l16(ksrc + (size_t)r * NSP + coff + g * 8, lds + 24576 + s * 16);
        }
        asm volatile("s_waitcnt vmcnt(0)" ::: "memory");
        __syncthreads();
#pragma unroll
        for (int j = 0; j < 2; ++j) {
            int c16 = (w * 2 + j) * 4 + lg;
            bf16x8 a[3], bb[3];
#pragma unroll
            for (int mf = 0; mf < 3; ++mf) {
                int r = mf * 16 + lr;
                a[mf] = *reinterpret_cast<const bf16x8*>(lds + r * 512 + ((c16 ^ (r & 7)) << 4));
            }
#pragma unroll
            for (int nf = 0; nf < 3; ++nf) {
                int r = nf * 16 + lr;
                bb[nf] = *reinterpret_cast<const bf16x8*>(lds + 24576 + r * 512 + ((c16 ^ (r & 7)) << 4));
            }
#pragma unroll
            for (int mf = 0; mf < 3; ++mf)
#pragma unroll
                for (int nf = 0; nf < 3; ++nf)
                    acc[mf][nf] = __builtin_amdgcn_mfma_f32_16x16x32_bf16(a[mf], bb[nf], acc[mf][nf], 0, 0, 0);
        }
    }
    __syncthreads();
    float* red = (float*)lds;
#pragma unroll
    for (int mf = 0; mf < 3; ++mf)
#pragma unroll
        for (int nf = 0; nf < 3; ++nf)
#pragma unroll
            for (int r = 0; r < 4; ++r) {
                int c = mf * 16 + lg * 4 + r, d = nf * 16 + lr;
                red[(w * 48 + c) * 49 + d] = acc[mf][nf][r];
            }
    __syncthreads();
    float* Sb = S + (size_t)(b * NHEADS + h) * NCH * NCH;
    for (int i = 0; i < 9; ++i) {
        int idx = t + i * 256;
        int c = idx / 48, d = idx % 48;
        float s = red[c * 49 + d] + red[(48 + c) * 49 + d] + red[(96 + c) * 49 + d] + red[(144 + c) * 49 + d];
        atomicAdd(&Sb[c * 48 + d], s);
    }
}

// ---------------- kernel 6: normalize + softmax + fold proj ----------------
__global__ __launch_bounds__(256) void k_soft(const float* __restrict__ S, const float* __restrict__ ssq,
                                              const float* __restrict__ temp, const float* __restrict__ w_proj,
                                              __bf16* __restrict__ M) {
    int b = blockIdx.x / NHEADS, h = blockIdx.x % NHEADS;
    int tid = threadIdx.x;
    __shared__ float attn[48][48];
    __shared__ float inv[96];
    if (tid < 96) {
        int c = tid % 48;
        int isK = tid / 48;
        float v = ssq[b * 384 + isK * 192 + h * NCH + c];
        float nrm = fmaxf(sqrtf(v), 1e-12f);
        inv[tid] = 1.f / nrm;
    }
    __syncthreads();
    float tp = temp[h];
    const float* Sb = S + (size_t)(b * NHEADS + h) * NCH * NCH;
    for (int i = 0; i < 9; ++i) {
        int idx = tid + i * 256;
        int c = idx / 48, d = idx % 48;
        attn[c][d] = Sb[c * 48 + d] * inv[c] * inv[48 + d] * tp;
    }
    __syncthreads();
    if (tid < 48) {
        float m = -1e30f;
        for (int d = 0; d < 48; ++d) m = fmaxf(m, attn[tid][d]);
        float sum = 0.f;
        for (int d = 0; d < 48; ++d) { float e = __expf(attn[tid][d] - m); attn[tid][d] = e; sum += e; }
        float r = 1.f / sum;
        for (int d = 0; d < 48; ++d) attn[tid][d] *= r;
    }
    __syncthreads();
    for (int i = 0; i < 36; ++i) {
        int idx = tid + i * 256;
        int oo = idx / 48, d = idx % 48;
        const float* wp = w_proj + oo * NC + h * NCH;
        float s = 0.f;
        for (int c = 0; c < 48; ++c) s += wp[c] * attn[c][d];
        M[(size_t)(b * NC + oo) * NC + h * NCH + d] = (__bf16)s;
    }
}

// ---------------- kernel 7: final GEMM, fused v-transpose staging, 3 A-tiles looped ----------------
__global__ __launch_bounds__(256, 2) void k_out(const __bf16* __restrict__ Mw, const __bf16* __restrict__ qkv2,
                                                float* __restrict__ outp) {
    __shared__ __align__(16) char lds[73728];
    int b = blockIdx.y, n0 = blockIdx.x * 128;
    int t = threadIdx.x;
    const __bf16* asrc0 = Mw + (size_t)(b * NC) * NC;
#pragma unroll
    for (int i = 0; i < 6; ++i) {
        int s = i * 256 + t;
        int r = s / 24, c = s % 24, g = c ^ GR(r);
        g2l16(asrc0 + (size_t)r * NC + g * 8, lds + 49152 + s * 16);
    }
    // B-tile: bf16x4 loads along n, scalar swizzled LDS writes
    const __bf16* vb = qkv2 + (size_t)(b * NO + 384) * NSP + n0;
#pragma unroll 4
    for (int p = 0; p < 24; ++p) {
        int id = p * 256 + t;
        int c = id >> 5, n4 = (id & 31) << 2;
        bf16x4 vv = *reinterpret_cast<const bf16x4*>(vb + (size_t)c * NSP + n4);
#pragma unroll
        for (int j = 0; j < 4; ++j) {
            int n = n4 + j;
            int chi = (c >> 3) ^ GR(n);
            *reinterpret_cast<__bf16*>((char*)lds + n * 384 + chi * 16 + (c & 7) * 2) = vv[j];
        }
    }
    asm volatile("s_waitcnt vmcnt(0)" ::: "memory");
    __syncthreads();
    int w = t >> 6, l = t & 63, lr = l & 15, lg = l >> 4;
    bf16x8 bgf[6][2];
#pragma unroll
    for (int ks = 0; ks < 6; ++ks) {
        int c16 = ks * 4 + lg;
#pragma unroll
        for (int nf = 0; nf < 2; ++nf) {
            int r = w * 32 + nf * 16 + lr;
            bgf[ks][nf] = *reinterpret_cast<const bf16x8*>(lds + r * 384 + ((c16 ^ GR(r)) << 4));
        }
    }
    for (int ot = 0; ot < 3; ++ot) {
        f32x4 acc[4][2] = {};
#pragma unroll
        for (int ks = 0; ks < 6; ++ks) {
            int c16 = ks * 4 + lg;
            bf16x8 a[4];
#pragma unroll
            for (int mf = 0; mf < 4; ++mf) {
                int r = mf * 16 + lr;
                a[mf] = *reinterpret_cast<const bf16x8*>(lds + 49152 + r * 384 + ((c16 ^ GR(r)) << 4));
            }
#pragma unroll
            for (int mf = 0; mf < 4; ++mf)
#pragma unroll
                for (int nf = 0; nf < 2; ++nf)
                    acc[mf][nf] = __builtin_amdgcn_mfma_f32_16x16x32_bf16(a[mf], bgf[ks][nf], acc[mf][nf], 0, 0, 0);
        }
        __syncthreads();
        if (ot < 2) {
            const __bf16* asrc = Mw + (size_t)(b * NC + (ot + 1) * 64) * NC;
#pragma unroll
            for (int i = 0; i < 6; ++i) {
                int s = i * 256 + t;
                int r = s / 24, c = s % 24, g = c ^ GR(r);
                g2l16(asrc + (size_t)r * NC + g * 8, lds + 49152 + s * 16);
            }
        }
        int o0 = ot * 64;
#pragma unroll
        for (int mf = 0; mf < 4; ++mf)
#pragma unroll
            for (int rr = 0; rr < 4; ++rr) {
                int orow = o0 + mf * 16 + lg * 4 + rr;
#pragma unroll
                for (int nf = 0; nf < 2; ++nf)
                    outp[(size_t)(b * NC + orow) * NSP + n0 + w * 32 + nf * 16 + lr] = acc[mf][nf][rr];
            }
        if (ot < 2) {
            asm volatile("s_waitcnt vmcnt(32)" ::: "memory");
            __syncthreads();
        }
    }
}

extern "C" void kernel_launch(void* const* d_in, const int* in_sizes, int n_in,
                              void* d_out, int out_size, void* d_ws, size_t ws_size,
                              hipStream_t stream) {
    const float* x        = (const float*)d_in[0];
    const float* prior    = (const float*)d_in[1];
    const float* w_qkv    = (const float*)d_in[2];
    const float* w_dw     = (const float*)d_in[3];
    const float* w_proj   = (const float*)d_in[4];
    const float* w_kernel = (const float*)d_in[5];
    const float* temp     = (const float*)d_in[6];
    char* ws = (char*)d_ws;
    float*  kv    = (float*)(ws + OFF_KV);
    float*  ssq   = (float*)(ws + OFF_SSQ);
    float*  S     = (float*)(ws + OFF_S);
    __bf16* Wb    = (__bf16*)(ws + OFF_WB);
    __bf16* M     = (__bf16*)(ws + OFF_M);
    __bf16* xt    = (__bf16*)(ws + OFF_XT);
    __bf16* qkv2  = (__bf16*)(ws + OFF_XT);    // aliases xt (xt dead after k_qkv)
    __bf16* qkv1  = (__bf16*)(ws + OFF_QKV1);
    float*  outp  = (float*)d_out;

    k_prep<<<432, 256, 0, stream>>>(prior, w_kernel, w_qkv, kv, (float*)(ws + OFF_SSQ), Wb);
    k_xt<<<dim3(128, 8), 256, 0, stream>>>(x, kv, xt);
    k_qkv<<<dim3(128, 8), 256, 0, stream>>>(xt, Wb, qkv1);
    k_dw<<<9216, 256, 0, stream>>>(qkv1, w_dw, qkv2, ssq);
    k_sdot<<<dim3(32, 4, 8), 256, 0, stream>>>(qkv2, S);
    k_soft<<<32, 256, 0, stream>>>(S, ssq, temp, w_proj, M);
    k_out<<<dim3(128, 8), 256, 0, stream>>>(M, qkv2, outp);
}